// Round 1
// baseline (386.568 us; speedup 1.0000x reference)
//
#include <hip/hip_runtime.h>
#include <hip/hip_bf16.h>
#include <cstdint>
#include <cstddef>

// Problem dims
#define SEQ 2048
#define DMODEL 1024
#define NHEAD 16
#define HDIM 64
#define MTOT 4096      // B*S
#define NQKV 3072
#define KDIM 1024

// d_out layout (floats): a[4194304] | k[4194304] | v[4194304]
#define OUT_A_ELEMS 4194304u
#define OUT_K_BASE  4194304u
#define OUT_V_BASE  8388608u

typedef __attribute__((ext_vector_type(4))) float f32x4;
typedef __attribute__((ext_vector_type(8))) __bf16 bf16x8;
typedef __attribute__((ext_vector_type(8))) short s16x8;
typedef __attribute__((ext_vector_type(4))) short s16x4;

static __device__ __forceinline__ unsigned short f2bf(float f) {
  unsigned int u = __builtin_bit_cast(unsigned int, f);
  u += 0x7FFFu + ((u >> 16) & 1u);
  return (unsigned short)(u >> 16);
}

static __device__ __forceinline__ s16x4 pack4(float4 v) {
  s16x4 r;
  r[0] = (short)f2bf(v.x);
  r[1] = (short)f2bf(v.y);
  r[2] = (short)f2bf(v.z);
  r[3] = (short)f2bf(v.w);
  return r;
}

static __device__ __forceinline__ f32x4 mfma16(s16x8 a, s16x8 b, f32x4 c) {
  return __builtin_amdgcn_mfma_f32_16x16x32_bf16(
      __builtin_bit_cast(bf16x8, a), __builtin_bit_cast(bf16x8, b), c, 0, 0, 0);
}

// ---------------------------------------------------------------------------
// Kernel 1: qkv = x @ c_attn_w + b; route q->ws(bf16,[B,H,S,hd]),
// k,v -> d_out present slots (fp32,[B,H,S,hd])
// ---------------------------------------------------------------------------
__global__ __launch_bounds__(256) void qkv_gemm(
    const float* __restrict__ X,     // [4096][1024]
    const float* __restrict__ W,     // [1024][3072]
    const float* __restrict__ Bias,  // [3072]
    float* __restrict__ out,         // d_out
    unsigned short* __restrict__ Qbf)
{
  __shared__ unsigned short lds_a[128][32];
  __shared__ unsigned short lds_b[32][132];   // +4 pad: breaks group bank aliasing

  const int tid = threadIdx.x;
  const int lane = tid & 63;
  const int wv = tid >> 6;
  const int wr = wv >> 1, wc = wv & 1;
  const int m0 = blockIdx.x * 128;
  const int n0 = blockIdx.y * 128;
  const int lr = lane & 15;
  const int ks = (lane >> 4) << 3;
  const int gq = lane >> 4;

  const f32x4 fzero = {0.f, 0.f, 0.f, 0.f};
  f32x4 acc[4][4];
#pragma unroll
  for (int i = 0; i < 4; ++i)
#pragma unroll
    for (int j = 0; j < 4; ++j) acc[i][j] = fzero;

  for (int k0 = 0; k0 < KDIM; k0 += 32) {
#pragma unroll
    for (int i = 0; i < 4; ++i) {
      int idx = tid + (i << 8);            // 0..1023
      int row = idx >> 3, c4 = (idx & 7) << 2;
      float4 v = *reinterpret_cast<const float4*>(&X[(size_t)(m0 + row) * KDIM + k0 + c4]);
      *reinterpret_cast<s16x4*>(&lds_a[row][c4]) = pack4(v);
    }
#pragma unroll
    for (int i = 0; i < 4; ++i) {
      int idx = tid + (i << 8);            // 0..1023
      int row = idx >> 5, c4 = (idx & 31) << 2;
      float4 v = *reinterpret_cast<const float4*>(&W[(size_t)(k0 + row) * NQKV + n0 + c4]);
      *reinterpret_cast<s16x4*>(&lds_b[row][c4]) = pack4(v);
    }
    __syncthreads();

    s16x8 af[4];
#pragma unroll
    for (int mi = 0; mi < 4; ++mi)
      af[mi] = *reinterpret_cast<const s16x8*>(&lds_a[wr * 64 + mi * 16 + lr][ks]);
#pragma unroll
    for (int ni = 0; ni < 4; ++ni) {
      int col = wc * 64 + ni * 16 + lr;
      s16x8 bfr;
#pragma unroll
      for (int jj = 0; jj < 8; ++jj) bfr[jj] = (short)lds_b[ks + jj][col];
#pragma unroll
      for (int mi = 0; mi < 4; ++mi) acc[mi][ni] = mfma16(af[mi], bfr, acc[mi][ni]);
    }
    __syncthreads();
  }

#pragma unroll
  for (int ni = 0; ni < 4; ++ni) {
    int c = n0 + wc * 64 + ni * 16 + lr;
    float bias = Bias[c];
    int seg = c >> 10;          // 0=q 1=k 2=v
    int cc = c & 1023;
    int h = cc >> 6, d = cc & 63;
#pragma unroll
    for (int mi = 0; mi < 4; ++mi) {
#pragma unroll
      for (int j = 0; j < 4; ++j) {
        int m = m0 + wr * 64 + mi * 16 + gq * 4 + j;
        int b = m >> 11, s = m & 2047;
        float val = acc[mi][ni][j] + bias;
        size_t idx = (size_t)((b * NHEAD + h) * SEQ + s) * HDIM + d;
        if (seg == 0)      Qbf[idx] = f2bf(val);
        else if (seg == 1) out[OUT_K_BASE + idx] = val;
        else               out[OUT_V_BASE + idx] = val;
      }
    }
  }
}

// ---------------------------------------------------------------------------
// Kernel 2: causal flash attention. 2 waves/block, 64 q-rows/wave.
// Reads Q(bf16,ws), K/V(fp32,d_out). Writes attn-out merged (bf16,ws).
// ---------------------------------------------------------------------------
__global__ __launch_bounds__(128) void attn_fwd(
    const unsigned short* __restrict__ Qbf,
    const float* __restrict__ outbuf,
    unsigned short* __restrict__ Abf)
{
  __shared__ unsigned short lds_k[64][64];     // XOR-swizzled cols
  __shared__ unsigned short lds_v[64][64];     // plain [kv][d]
  __shared__ unsigned short lds_p[2][64][64];  // per-wave, XOR-swizzled cols

  const int tid = threadIdx.x;
  const int lane = tid & 63;
  const int wv = tid >> 6;
  const int bid = blockIdx.x;       // bh*16 + qB
  const int qB = bid & 15;
  const int bh = bid >> 4;          // b*16+h
  const int qw0 = qB * 128 + wv * 64;

  const float* Kg = outbuf + OUT_K_BASE + (size_t)bh * (SEQ * HDIM);
  const float* Vg = outbuf + OUT_V_BASE + (size_t)bh * (SEQ * HDIM);
  const unsigned short* Qg = Qbf + (size_t)bh * (SEQ * HDIM);

  const int lr = lane & 15;
  const int ks = (lane >> 4) << 3;
  const int gq = lane >> 4;

  // Q fragments for this wave's 64 rows (A-operand layout)
  s16x8 qf[4][2];
#pragma unroll
  for (int mi = 0; mi < 4; ++mi)
#pragma unroll
    for (int kf = 0; kf < 2; ++kf)
      qf[mi][kf] = *reinterpret_cast<const s16x8*>(
          &Qg[(size_t)(qw0 + mi * 16 + lr) * HDIM + kf * 32 + ks]);

  const f32x4 fzero = {0.f, 0.f, 0.f, 0.f};
  f32x4 O[4][4];
  float m_row[4][4], l_row[4][4];
#pragma unroll
  for (int mi = 0; mi < 4; ++mi)
#pragma unroll
    for (int j = 0; j < 4; ++j) { m_row[mi][j] = -1e30f; l_row[mi][j] = 0.f; }
#pragma unroll
  for (int mi = 0; mi < 4; ++mi)
#pragma unroll
    for (int ni = 0; ni < 4; ++ni) O[mi][ni] = fzero;

  const int ntiles = qB * 2 + 2;
  for (int t = 0; t < ntiles; ++t) {
    const int kv0 = t * 64;
    // cooperative staging: K and V tiles (64x64 fp32 -> bf16)
#pragma unroll
    for (int i = 0; i < 8; ++i) {
      int idx = tid + (i << 7);            // 0..1023 float4 slots
      int row = idx >> 4, c4 = (idx & 15) << 2;
      float4 kvv = *reinterpret_cast<const float4*>(&Kg[(size_t)(kv0 + row) * HDIM + c4]);
      *reinterpret_cast<s16x4*>(&lds_k[row][c4 ^ ((row & 7) << 3)]) = pack4(kvv);
      float4 vvv = *reinterpret_cast<const float4*>(&Vg[(size_t)(kv0 + row) * HDIM + c4]);
      *reinterpret_cast<s16x4*>(&lds_v[row][c4]) = pack4(vvv);
    }
    __syncthreads();

    if (kv0 <= qw0) {
      // S = Q K^T  (B-frag = K rows read contiguous, swizzled)
      f32x4 sc[4][4];
#pragma unroll
      for (int ni = 0; ni < 4; ++ni) {
        int srow = ni * 16 + lr;
        int sw = (srow & 7) << 3;
        s16x8 kb0 = *reinterpret_cast<const s16x8*>(&lds_k[srow][ks ^ sw]);
        s16x8 kb1 = *reinterpret_cast<const s16x8*>(&lds_k[srow][(32 + ks) ^ sw]);
#pragma unroll
        for (int mi = 0; mi < 4; ++mi) {
          f32x4 tacc = fzero;
          tacc = mfma16(qf[mi][0], kb0, tacc);
          tacc = mfma16(qf[mi][1], kb1, tacc);
          sc[mi][ni] = tacc;
        }
      }
      const bool diag = (kv0 == qw0);
      // scale + causal mask
#pragma unroll
      for (int mi = 0; mi < 4; ++mi)
#pragma unroll
        for (int ni = 0; ni < 4; ++ni)
#pragma unroll
          for (int j = 0; j < 4; ++j) {
            float v = sc[mi][ni][j] * 0.125f;
            if (diag) {
              int r = mi * 16 + gq * 4 + j;
              int cl = ni * 16 + lr;
              if (cl > r) v = -1e30f;
            }
            sc[mi][ni][j] = v;
          }
      // online softmax per row; write P (bf16) to this wave's LDS buffer
#pragma unroll
      for (int mi = 0; mi < 4; ++mi) {
#pragma unroll
        for (int j = 0; j < 4; ++j) {
          float tmax = fmaxf(fmaxf(sc[mi][0][j], sc[mi][1][j]),
                             fmaxf(sc[mi][2][j], sc[mi][3][j]));
#pragma unroll
          for (int off = 1; off < 16; off <<= 1)
            tmax = fmaxf(tmax, __shfl_xor(tmax, off));
          float newm = fmaxf(m_row[mi][j], tmax);
          float fs = __expf(m_row[mi][j] - newm);
          m_row[mi][j] = newm;
          l_row[mi][j] *= fs;
#pragma unroll
          for (int ni = 0; ni < 4; ++ni) O[mi][ni][j] *= fs;
          float rs = 0.f;
#pragma unroll
          for (int ni = 0; ni < 4; ++ni) {
            float p = __expf(sc[mi][ni][j] - newm);
            sc[mi][ni][j] = p;
            rs += p;
          }
#pragma unroll
          for (int off = 1; off < 16; off <<= 1)
            rs += __shfl_xor(rs, off);
          l_row[mi][j] += rs;
          int r = mi * 16 + gq * 4 + j;
          int sw = (r & 7) << 3;
#pragma unroll
          for (int ni = 0; ni < 4; ++ni)
            lds_p[wv][r][(ni * 16 + lr) ^ sw] = f2bf(sc[mi][ni][j]);
        }
      }
      // O += P V  (A-frag = P from LDS; B-frag = V scalar reads, 4-way ok)
      s16x8 pf[4][2];
#pragma unroll
      for (int mi = 0; mi < 4; ++mi) {
        int r = mi * 16 + lr;
        int sw = (r & 7) << 3;
        pf[mi][0] = *reinterpret_cast<const s16x8*>(&lds_p[wv][r][ks ^ sw]);
        pf[mi][1] = *reinterpret_cast<const s16x8*>(&lds_p[wv][r][(32 + ks) ^ sw]);
      }
#pragma unroll
      for (int ni = 0; ni < 4; ++ni) {
        s16x8 vb0, vb1;
#pragma unroll
        for (int jj = 0; jj < 8; ++jj) {
          vb0[jj] = (short)lds_v[ks + jj][ni * 16 + lr];
          vb1[jj] = (short)lds_v[32 + ks + jj][ni * 16 + lr];
        }
#pragma unroll
        for (int mi = 0; mi < 4; ++mi) {
          O[mi][ni] = mfma16(pf[mi][0], vb0, O[mi][ni]);
          O[mi][ni] = mfma16(pf[mi][1], vb1, O[mi][ni]);
        }
      }
    }
    __syncthreads();
  }

  // normalize + write merged attn-out (bf16) to ws
  const int b = bh >> 4, h = bh & 15;
#pragma unroll
  for (int mi = 0; mi < 4; ++mi)
#pragma unroll
    for (int j = 0; j < 4; ++j) {
      float inv = 1.0f / l_row[mi][j];
      int s = qw0 + mi * 16 + gq * 4 + j;
#pragma unroll
      for (int ni = 0; ni < 4; ++ni) {
        int c = h * 64 + ni * 16 + lr;
        Abf[(size_t)(b * SEQ + s) * DMODEL + c] = f2bf(O[mi][ni][j] * inv);
      }
    }
}

// ---------------------------------------------------------------------------
// Kernel 3: out = attn @ c_proj_w + b
// ---------------------------------------------------------------------------
__global__ __launch_bounds__(256) void proj_gemm(
    const unsigned short* __restrict__ Abf,  // [4096][1024] bf16
    const float* __restrict__ W,             // [1024][1024]
    const float* __restrict__ Bias,          // [1024]
    float* __restrict__ out)                 // [4096][1024]
{
  __shared__ unsigned short lds_a[128][32];
  __shared__ unsigned short lds_b[32][132];

  const int tid = threadIdx.x;
  const int lane = tid & 63;
  const int wv = tid >> 6;
  const int wr = wv >> 1, wc = wv & 1;
  const int m0 = blockIdx.x * 128;
  const int n0 = blockIdx.y * 128;
  const int lr = lane & 15;
  const int ks = (lane >> 4) << 3;
  const int gq = lane >> 4;

  const f32x4 fzero = {0.f, 0.f, 0.f, 0.f};
  f32x4 acc[4][4];
#pragma unroll
  for (int i = 0; i < 4; ++i)
#pragma unroll
    for (int j = 0; j < 4; ++j) acc[i][j] = fzero;

  for (int k0 = 0; k0 < KDIM; k0 += 32) {
#pragma unroll
    for (int i = 0; i < 2; ++i) {
      int idx = tid + (i << 8);          // 0..511 (8-ushort chunks)
      int row = idx >> 2, c8 = (idx & 3) << 3;
      *reinterpret_cast<s16x8*>(&lds_a[row][c8]) =
          *reinterpret_cast<const s16x8*>(&Abf[(size_t)(m0 + row) * KDIM + k0 + c8]);
    }
#pragma unroll
    for (int i = 0; i < 4; ++i) {
      int idx = tid + (i << 8);
      int row = idx >> 5, c4 = (idx & 31) << 2;
      float4 v = *reinterpret_cast<const float4*>(&W[(size_t)(k0 + row) * DMODEL + n0 + c4]);
      *reinterpret_cast<s16x4*>(&lds_b[row][c4]) = pack4(v);
    }
    __syncthreads();

    s16x8 af[4];
#pragma unroll
    for (int mi = 0; mi < 4; ++mi)
      af[mi] = *reinterpret_cast<const s16x8*>(&lds_a[wr * 64 + mi * 16 + lr][ks]);
#pragma unroll
    for (int ni = 0; ni < 4; ++ni) {
      int col = wc * 64 + ni * 16 + lr;
      s16x8 bfr;
#pragma unroll
      for (int jj = 0; jj < 8; ++jj) bfr[jj] = (short)lds_b[ks + jj][col];
#pragma unroll
      for (int mi = 0; mi < 4; ++mi) acc[mi][ni] = mfma16(af[mi], bfr, acc[mi][ni]);
    }
    __syncthreads();
  }

#pragma unroll
  for (int ni = 0; ni < 4; ++ni) {
    int c = n0 + wc * 64 + ni * 16 + lr;
    float bias = Bias[c];
#pragma unroll
    for (int mi = 0; mi < 4; ++mi) {
#pragma unroll
      for (int j = 0; j < 4; ++j) {
        int m = m0 + wr * 64 + mi * 16 + gq * 4 + j;
        out[(size_t)m * DMODEL + c] = acc[mi][ni][j] + bias;
      }
    }
  }
}

// ---------------------------------------------------------------------------
extern "C" void kernel_launch(void* const* d_in, const int* in_sizes, int n_in,
                              void* d_out, int out_size, void* d_ws, size_t ws_size,
                              hipStream_t stream) {
  const float* x        = (const float*)d_in[0];
  const float* c_attn_w = (const float*)d_in[1];
  const float* c_attn_b = (const float*)d_in[2];
  const float* c_proj_w = (const float*)d_in[3];
  const float* c_proj_b = (const float*)d_in[4];
  float* out = (float*)d_out;

  unsigned short* Qbf = (unsigned short*)d_ws;          // 4194304 bf16 = 8 MiB
  unsigned short* Abf = Qbf + 4194304;                  // 4194304 bf16 = 8 MiB

  qkv_gemm<<<dim3(32, 24), 256, 0, stream>>>(x, c_attn_w, c_attn_b, out, Qbf);
  attn_fwd<<<dim3(512), 128, 0, stream>>>(Qbf, out, Abf);
  proj_gemm<<<dim3(32, 8), 256, 0, stream>>>(Abf, c_proj_w, c_proj_b, out);
}

// Round 2
// 167.634 us; speedup vs baseline: 2.3060x; 2.3060x over previous
//
#include <hip/hip_runtime.h>
#include <hip/hip_bf16.h>
#include <cstdint>
#include <cstddef>

// Problem dims
#define SEQ 2048
#define DMODEL 1024
#define NHEAD 16
#define HDIM 64
#define MTOT 4096      // B*S
#define NQKV 3072
#define KDIM 1024

// d_out layout (floats): a[4194304] | k[4194304] | v[4194304]
#define OUT_K_BASE  4194304u
#define OUT_V_BASE  8388608u

// 0.125 * log2(e): folded into Q so QK^T scores are already in exp2 domain
#define QSCALE 0.18033688011112043f

typedef __attribute__((ext_vector_type(4))) float f32x4;
typedef __attribute__((ext_vector_type(8))) __bf16 bf16x8;
typedef __attribute__((ext_vector_type(8))) short s16x8;
typedef __attribute__((ext_vector_type(4))) short s16x4;

static __device__ __forceinline__ unsigned short f2bf(float f) {
  unsigned int u = __builtin_bit_cast(unsigned int, f);
  u += 0x7FFFu + ((u >> 16) & 1u);
  return (unsigned short)(u >> 16);
}

static __device__ __forceinline__ s16x4 pack4(float4 v) {
  s16x4 r;
  r[0] = (short)f2bf(v.x);
  r[1] = (short)f2bf(v.y);
  r[2] = (short)f2bf(v.z);
  r[3] = (short)f2bf(v.w);
  return r;
}

static __device__ __forceinline__ f32x4 mfma16(s16x8 a, s16x8 b, f32x4 c) {
  return __builtin_amdgcn_mfma_f32_16x16x32_bf16(
      __builtin_bit_cast(bf16x8, a), __builtin_bit_cast(bf16x8, b), c, 0, 0, 0);
}

// async global->LDS, 16B per lane. LDS dest: wave-uniform base + lane*16.
static __device__ __forceinline__ void gload16(const void* g, void* l) {
  __builtin_amdgcn_global_load_lds(
      (const __attribute__((address_space(1))) unsigned int*)(uintptr_t)g,
      (__attribute__((address_space(3))) unsigned int*)(uintptr_t)l,
      16, 0, 0);
}

// ---------------------------------------------------------------------------
// Kernel 1: qkv = x @ c_attn_w + b.
//   q -> Qbf (ws, bf16, [B,H,S,hd], pre-scaled by 0.125*log2e)
//   k -> d_out present slot (fp32) AND Kbf (bf16, [B,H,S,hd], in a-slot)
//   v -> d_out present slot (fp32) AND Vt  (bf16, [B,H,hd,S], in a-slot)
// ---------------------------------------------------------------------------
__global__ __launch_bounds__(256) void qkv_gemm(
    const float* __restrict__ X,     // [4096][1024]
    const float* __restrict__ W,     // [1024][3072]
    const float* __restrict__ Bias,  // [3072]
    float* out,                      // d_out
    unsigned short* __restrict__ Qbf)
{
  __shared__ unsigned short lds_a[128][32];
  __shared__ unsigned short lds_b[32][132];

  unsigned short* Kbf = (unsigned short*)out;   // a-slot scratch, 8 MiB
  unsigned short* Vt  = Kbf + 4194304;          // a-slot scratch, 8 MiB

  const int tid = threadIdx.x;
  const int lane = tid & 63;
  const int wv = tid >> 6;
  const int wr = wv >> 1, wc = wv & 1;
  const int m0 = blockIdx.x * 128;
  const int n0 = blockIdx.y * 128;
  const int lr = lane & 15;
  const int ks = (lane >> 4) << 3;
  const int gq = lane >> 4;

  const f32x4 fzero = {0.f, 0.f, 0.f, 0.f};
  f32x4 acc[4][4];
#pragma unroll
  for (int i = 0; i < 4; ++i)
#pragma unroll
    for (int j = 0; j < 4; ++j) acc[i][j] = fzero;

  for (int k0 = 0; k0 < KDIM; k0 += 32) {
#pragma unroll
    for (int i = 0; i < 4; ++i) {
      int idx = tid + (i << 8);
      int row = idx >> 3, c4 = (idx & 7) << 2;
      float4 v = *reinterpret_cast<const float4*>(&X[(size_t)(m0 + row) * KDIM + k0 + c4]);
      *reinterpret_cast<s16x4*>(&lds_a[row][c4]) = pack4(v);
    }
#pragma unroll
    for (int i = 0; i < 4; ++i) {
      int idx = tid + (i << 8);
      int row = idx >> 5, c4 = (idx & 31) << 2;
      float4 v = *reinterpret_cast<const float4*>(&W[(size_t)(k0 + row) * NQKV + n0 + c4]);
      *reinterpret_cast<s16x4*>(&lds_b[row][c4]) = pack4(v);
    }
    __syncthreads();

    s16x8 af[4];
#pragma unroll
    for (int mi = 0; mi < 4; ++mi)
      af[mi] = *reinterpret_cast<const s16x8*>(&lds_a[wr * 64 + mi * 16 + lr][ks]);
#pragma unroll
    for (int ni = 0; ni < 4; ++ni) {
      int col = wc * 64 + ni * 16 + lr;
      s16x8 bfr;
#pragma unroll
      for (int jj = 0; jj < 8; ++jj) bfr[jj] = (short)lds_b[ks + jj][col];
#pragma unroll
      for (int mi = 0; mi < 4; ++mi) acc[mi][ni] = mfma16(af[mi], bfr, acc[mi][ni]);
    }
    __syncthreads();
  }

#pragma unroll
  for (int ni = 0; ni < 4; ++ni) {
    int c = n0 + wc * 64 + ni * 16 + lr;
    float bias = Bias[c];
    int seg = c >> 10;          // 0=q 1=k 2=v
    int cc = c & 1023;
    int h = cc >> 6, d = cc & 63;
#pragma unroll
    for (int mi = 0; mi < 4; ++mi) {
#pragma unroll
      for (int j = 0; j < 4; ++j) {
        int m = m0 + wr * 64 + mi * 16 + gq * 4 + j;
        int b = m >> 11, s = m & 2047;
        float val = acc[mi][ni][j] + bias;
        size_t idx = (size_t)((b * NHEAD + h) * SEQ + s) * HDIM + d;
        if (seg == 0) {
          Qbf[idx] = f2bf(val * QSCALE);
        } else if (seg == 1) {
          out[OUT_K_BASE + idx] = val;
          Kbf[idx] = f2bf(val);
        } else {
          out[OUT_V_BASE + idx] = val;
          Vt[((size_t)(b * NHEAD + h) * HDIM + d) * SEQ + s] = f2bf(val);
        }
      }
    }
  }
}

// ---------------------------------------------------------------------------
// Kernel 2: causal flash attention.
// Block = 64-row q-tile (4 waves x 16 rows). K/V double-buffered in LDS via
// global_load_lds with pre-swizzled source (chunk c of row r holds global
// chunk c^(r&7)) so all b128 fragment reads are bank-conflict-free.
// ---------------------------------------------------------------------------
__global__ __launch_bounds__(256, 4) void attn_fwd(
    const unsigned short* __restrict__ Qbf,  // pre-scaled bf16 [bh][s][d]
    const unsigned short* __restrict__ Kbf,  // bf16 [bh][s][d]
    const unsigned short* __restrict__ Vtg,  // bf16 [bh][d][s]
    unsigned short* __restrict__ Abf)        // bf16 [b][s][D] merged heads
{
  __shared__ __align__(16) unsigned short K_lds[2][64][64];
  __shared__ __align__(16) unsigned short V_lds[2][64][64];
  __shared__ __align__(16) unsigned short P_lds[4][16][64];

  const int tid = threadIdx.x;
  const int lane = tid & 63;
  const int wv = tid >> 6;
  const int bid = blockIdx.x;
  const int qt = 31 - (bid >> 5);   // longest blocks dispatch first (LPT)
  const int bh = bid & 31;

  const int lr = lane & 15;
  const int gq = lane >> 4;
  const int ks = gq << 3;

  const unsigned short* Kg = Kbf + (size_t)bh * (SEQ * HDIM);
  const unsigned short* Vg = Vtg + (size_t)bh * (SEQ * HDIM);
  const unsigned short* Qg = Qbf + (size_t)bh * (SEQ * HDIM)
                                 + (size_t)(qt * 64 + wv * 16) * HDIM;

  // Q fragments (A-operand): row=lr, k=ks+j (+32 for second half)
  s16x8 qf0 = *reinterpret_cast<const s16x8*>(&Qg[lr * 64 + ks]);
  s16x8 qf1 = *reinterpret_cast<const s16x8*>(&Qg[lr * 64 + 32 + ks]);

  const f32x4 fzero = {0.f, 0.f, 0.f, 0.f};
  f32x4 O[4];
  float mrow[4], lrow[4];
#pragma unroll
  for (int j = 0; j < 4; ++j) { mrow[j] = -1e30f; lrow[j] = 0.f; O[j] = fzero; }
  // note: O[ni] indexes the 4 column-fragments; mrow/lrow index j (row within 4)

  // --- staging helper (inlined twice) ---
  // pass i: threads cover LDS 16B-chunks L = tid + i*256; r=L>>3, c=L&7.
  // LDS[r][chunk c] <- global row r, chunk c^(r&7).
#define STAGE(kv0, nb)                                                        \
  {                                                                           \
    _Pragma("unroll")                                                         \
    for (int i = 0; i < 2; ++i) {                                             \
      int L = tid + (i << 8);                                                 \
      int r = L >> 3, c = L & 7;                                              \
      int cc = (c ^ (r & 7)) << 3;                                            \
      int ubase = ((i << 8) + (wv << 6)) << 3; /* wave-uniform elem base */   \
      gload16(&Kg[(((kv0) + r) << 6) + cc], &K_lds[nb][0][0] + ubase);        \
      gload16(&Vg[((size_t)r << 11) + (kv0) + cc], &V_lds[nb][0][0] + ubase); \
    }                                                                         \
  }

  STAGE(0, 0);

  for (int t = 0; t <= qt; ++t) {
    __syncthreads();                       // buf[t&1] staged; prev compute done
    if (t < qt) STAGE((t + 1) * 64, (t + 1) & 1);
    const int buf = t & 1;

    // ---- S = Q K^T (pre-scaled, exp2 domain) ----
    f32x4 sc[4];
#pragma unroll
    for (int ni = 0; ni < 4; ++ni) {
      int kr = ni * 16 + lr;
      int sw = kr & 7;
      s16x8 kb0 = *reinterpret_cast<const s16x8*>(&K_lds[buf][kr][(gq ^ sw) << 3]);
      s16x8 kb1 = *reinterpret_cast<const s16x8*>(&K_lds[buf][kr][((gq + 4) ^ sw) << 3]);
      f32x4 tacc = mfma16(qf0, kb0, fzero);
      sc[ni] = mfma16(qf1, kb1, tacc);
    }

    // ---- causal mask (diag tile only) ----
    if (t == qt) {
#pragma unroll
      for (int ni = 0; ni < 4; ++ni) {
        int cl = ni * 16 + lr;
#pragma unroll
        for (int j = 0; j < 4; ++j) {
          int rb = wv * 16 + gq * 4 + j;
          if (cl > rb) sc[ni][j] = -1e30f;
        }
      }
    }

    // ---- online softmax (16 rows/wave; row rr = gq*4+j, cols over ni,lr) ----
#pragma unroll
    for (int j = 0; j < 4; ++j) {
      float tmax = fmaxf(fmaxf(sc[0][j], sc[1][j]), fmaxf(sc[2][j], sc[3][j]));
#pragma unroll
      for (int off = 1; off < 16; off <<= 1)
        tmax = fmaxf(tmax, __shfl_xor(tmax, off));
      float newm = fmaxf(mrow[j], tmax);
      float fs = __builtin_amdgcn_exp2f(mrow[j] - newm);
      mrow[j] = newm;
      float p0 = __builtin_amdgcn_exp2f(sc[0][j] - newm);
      float p1 = __builtin_amdgcn_exp2f(sc[1][j] - newm);
      float p2 = __builtin_amdgcn_exp2f(sc[2][j] - newm);
      float p3 = __builtin_amdgcn_exp2f(sc[3][j] - newm);
      float rs = (p0 + p1) + (p2 + p3);
#pragma unroll
      for (int off = 1; off < 16; off <<= 1)
        rs += __shfl_xor(rs, off);
      lrow[j] = lrow[j] * fs + rs;
#pragma unroll
      for (int ni = 0; ni < 4; ++ni) O[ni][j] *= fs;
      int rr = gq * 4 + j;
      int swp = rr & 7;
      // P element e = ni*16+lr -> LDS chunk (e>>3)^(rr&7), pos e&7
      P_lds[wv][rr][((((0 * 2) + (lr >> 3)) ^ swp) << 3) | (lr & 7)] = f2bf(p0);
      P_lds[wv][rr][((((1 * 2) + (lr >> 3)) ^ swp) << 3) | (lr & 7)] = f2bf(p1);
      P_lds[wv][rr][((((2 * 2) + (lr >> 3)) ^ swp) << 3) | (lr & 7)] = f2bf(p2);
      P_lds[wv][rr][((((3 * 2) + (lr >> 3)) ^ swp) << 3) | (lr & 7)] = f2bf(p3);
    }

    // ---- O += P V ----
    {
      int swl = lr & 7;
      s16x8 pf0 = *reinterpret_cast<const s16x8*>(&P_lds[wv][lr][(gq ^ swl) << 3]);
      s16x8 pf1 = *reinterpret_cast<const s16x8*>(&P_lds[wv][lr][((gq + 4) ^ swl) << 3]);
#pragma unroll
      for (int ni = 0; ni < 4; ++ni) {
        int dr = ni * 16 + lr;
        int sw = dr & 7;
        s16x8 vb0 = *reinterpret_cast<const s16x8*>(&V_lds[buf][dr][(gq ^ sw) << 3]);
        s16x8 vb1 = *reinterpret_cast<const s16x8*>(&V_lds[buf][dr][((gq + 4) ^ sw) << 3]);
        O[ni] = mfma16(pf0, vb0, O[ni]);
        O[ni] = mfma16(pf1, vb1, O[ni]);
      }
    }
  }

  // ---- normalize + write merged heads (bf16) ----
  const int b = bh >> 4, h = bh & 15;
#pragma unroll
  for (int j = 0; j < 4; ++j) {
    float inv = 1.0f / lrow[j];
    int s = qt * 64 + wv * 16 + gq * 4 + j;
#pragma unroll
    for (int ni = 0; ni < 4; ++ni) {
      Abf[(size_t)(b * SEQ + s) * DMODEL + h * 64 + ni * 16 + lr] =
          f2bf(O[ni][j] * inv);
    }
  }
#undef STAGE
}

// ---------------------------------------------------------------------------
// Kernel 3: out = attn @ c_proj_w + b   (overwrites a-slot scratch)
// ---------------------------------------------------------------------------
__global__ __launch_bounds__(256) void proj_gemm(
    const unsigned short* __restrict__ Abf,  // [4096][1024] bf16
    const float* __restrict__ W,             // [1024][1024]
    const float* __restrict__ Bias,          // [1024]
    float* __restrict__ out)                 // [4096][1024]
{
  __shared__ unsigned short lds_a[128][32];
  __shared__ unsigned short lds_b[32][132];

  const int tid = threadIdx.x;
  const int lane = tid & 63;
  const int wv = tid >> 6;
  const int wr = wv >> 1, wc = wv & 1;
  const int m0 = blockIdx.x * 128;
  const int n0 = blockIdx.y * 128;
  const int lr = lane & 15;
  const int ks = (lane >> 4) << 3;
  const int gq = lane >> 4;

  const f32x4 fzero = {0.f, 0.f, 0.f, 0.f};
  f32x4 acc[4][4];
#pragma unroll
  for (int i = 0; i < 4; ++i)
#pragma unroll
    for (int j = 0; j < 4; ++j) acc[i][j] = fzero;

  for (int k0 = 0; k0 < KDIM; k0 += 32) {
#pragma unroll
    for (int i = 0; i < 2; ++i) {
      int idx = tid + (i << 8);
      int row = idx >> 2, c8 = (idx & 3) << 3;
      *reinterpret_cast<s16x8*>(&lds_a[row][c8]) =
          *reinterpret_cast<const s16x8*>(&Abf[(size_t)(m0 + row) * KDIM + k0 + c8]);
    }
#pragma unroll
    for (int i = 0; i < 4; ++i) {
      int idx = tid + (i << 8);
      int row = idx >> 5, c4 = (idx & 31) << 2;
      float4 v = *reinterpret_cast<const float4*>(&W[(size_t)(k0 + row) * DMODEL + n0 + c4]);
      *reinterpret_cast<s16x4*>(&lds_b[row][c4]) = pack4(v);
    }
    __syncthreads();

    s16x8 af[4];
#pragma unroll
    for (int mi = 0; mi < 4; ++mi)
      af[mi] = *reinterpret_cast<const s16x8*>(&lds_a[wr * 64 + mi * 16 + lr][ks]);
#pragma unroll
    for (int ni = 0; ni < 4; ++ni) {
      int col = wc * 64 + ni * 16 + lr;
      s16x8 bfr;
#pragma unroll
      for (int jj = 0; jj < 8; ++jj) bfr[jj] = (short)lds_b[ks + jj][col];
#pragma unroll
      for (int mi = 0; mi < 4; ++mi) acc[mi][ni] = mfma16(af[mi], bfr, acc[mi][ni]);
    }
    __syncthreads();
  }

#pragma unroll
  for (int ni = 0; ni < 4; ++ni) {
    int c = n0 + wc * 64 + ni * 16 + lr;
    float bias = Bias[c];
#pragma unroll
    for (int mi = 0; mi < 4; ++mi) {
#pragma unroll
      for (int j = 0; j < 4; ++j) {
        int m = m0 + wr * 64 + mi * 16 + gq * 4 + j;
        out[(size_t)m * DMODEL + c] = acc[mi][ni][j] + bias;
      }
    }
  }
}

// ---------------------------------------------------------------------------
extern "C" void kernel_launch(void* const* d_in, const int* in_sizes, int n_in,
                              void* d_out, int out_size, void* d_ws, size_t ws_size,
                              hipStream_t stream) {
  const float* x        = (const float*)d_in[0];
  const float* c_attn_w = (const float*)d_in[1];
  const float* c_attn_b = (const float*)d_in[2];
  const float* c_proj_w = (const float*)d_in[3];
  const float* c_proj_b = (const float*)d_in[4];
  float* out = (float*)d_out;

  unsigned short* Qbf = (unsigned short*)d_ws;   // 8 MiB
  unsigned short* Abf = Qbf + 4194304;           // 8 MiB
  unsigned short* Kbf = (unsigned short*)out;    // a-slot scratch (overwritten by proj)
  unsigned short* Vt  = Kbf + 4194304;

  qkv_gemm<<<dim3(32, 24), 256, 0, stream>>>(x, c_attn_w, c_attn_b, out, Qbf);
  attn_fwd<<<dim3(1024), 256, 0, stream>>>(Qbf, Kbf, Vt, Abf);
  proj_gemm<<<dim3(32, 8), 256, 0, stream>>>(Abf, c_proj_w, c_proj_b, out);
}

// Round 3
// 144.027 us; speedup vs baseline: 2.6840x; 1.1639x over previous
//
#include <hip/hip_runtime.h>
#include <hip/hip_bf16.h>
#include <cstdint>
#include <cstddef>

// Problem dims
#define SEQ 2048
#define DMODEL 1024
#define NHEAD 16
#define HDIM 64
#define MTOT 4096      // B*S
#define NQKV 3072
#define KDIM 1024

// d_out layout (floats): a[4194304] | k[4194304] | v[4194304]
#define OUT_K_BASE  4194304u
#define OUT_V_BASE  8388608u

// 0.125 * log2(e): folded into Q so QK^T scores are already in exp2 domain
#define QSCALE 0.18033688011112043f

typedef __attribute__((ext_vector_type(4))) float f32x4;
typedef __attribute__((ext_vector_type(8))) __bf16 bf16x8;
typedef __attribute__((ext_vector_type(8))) short s16x8;
typedef __attribute__((ext_vector_type(4))) short s16x4;

static __device__ __forceinline__ unsigned short f2bf(float f) {
  unsigned int u = __builtin_bit_cast(unsigned int, f);
  u += 0x7FFFu + ((u >> 16) & 1u);
  return (unsigned short)(u >> 16);
}

static __device__ __forceinline__ s16x4 pack4(float4 v) {
  s16x4 r;
  r[0] = (short)f2bf(v.x);
  r[1] = (short)f2bf(v.y);
  r[2] = (short)f2bf(v.z);
  r[3] = (short)f2bf(v.w);
  return r;
}

static __device__ __forceinline__ f32x4 mfma16(s16x8 a, s16x8 b, f32x4 c) {
  return __builtin_amdgcn_mfma_f32_16x16x32_bf16(
      __builtin_bit_cast(bf16x8, a), __builtin_bit_cast(bf16x8, b), c, 0, 0, 0);
}

// async global->LDS, 16B per lane. LDS dest: wave-uniform base + lane*16.
static __device__ __forceinline__ void gload16(const void* g, void* l) {
  __builtin_amdgcn_global_load_lds(
      (const __attribute__((address_space(1))) unsigned int*)(uintptr_t)g,
      (__attribute__((address_space(3))) unsigned int*)(uintptr_t)l,
      16, 0, 0);
}

// ---------------------------------------------------------------------------
// Pre-pass: X (fp32 [4096][1024]) -> Xbf (bf16, same layout)
// ---------------------------------------------------------------------------
__global__ __launch_bounds__(256) void convert_x(
    const float* __restrict__ X, unsigned short* __restrict__ Xbf)
{
  int i = blockIdx.x * 256 + threadIdx.x;   // float4 index, 1M total
  float4 v = reinterpret_cast<const float4*>(X)[i];
  reinterpret_cast<s16x4*>(Xbf)[i] = pack4(v);
}

// ---------------------------------------------------------------------------
// Pre-pass: W (fp32 [1024][N]) -> Wt (bf16 [N][1024]) tiled transpose via LDS
// grid = (N/64, 16)
// ---------------------------------------------------------------------------
__global__ __launch_bounds__(256) void convert_wt(
    const float* __restrict__ W, unsigned short* __restrict__ Wt, int N)
{
  __shared__ unsigned short t[64][72];   // pad 8: col reads hit distinct banks
  const int n0 = blockIdx.x * 64, k0 = blockIdx.y * 64;
  const int tid = threadIdx.x;
#pragma unroll
  for (int i = 0; i < 4; ++i) {
    int f = tid + (i << 8);              // 0..1023 float4 slots
    int r = f >> 4, c4 = (f & 15) << 2;
    float4 v = *reinterpret_cast<const float4*>(&W[(size_t)(k0 + r) * N + n0 + c4]);
    *reinterpret_cast<s16x4*>(&t[r][c4]) = pack4(v);
  }
  __syncthreads();
#pragma unroll
  for (int i = 0; i < 2; ++i) {
    int g = tid + (i << 8);              // 0..511 8-elem chunks
    int n = g >> 3, k8 = (g & 7) << 3;
    s16x8 o;
#pragma unroll
    for (int jj = 0; jj < 8; ++jj) o[jj] = (short)t[k8 + jj][n];
    *reinterpret_cast<s16x8*>(&Wt[(size_t)(n0 + n) * KDIM + k0 + k8]) = o;
  }
}

// ---------------------------------------------------------------------------
// m97-structure GEMM main loop (macro shared by both GEMM kernels).
// A: bf16 [M][1024] row-major; Bt: bf16 [N][1024] row-major (= B transposed).
// 128x128 tile, 4 waves (2x2 of 64x64), BK=32, global_load_lds staging,
// all fragment reads ds_read_b128.
// ---------------------------------------------------------------------------
#define GEMM_MAIN_LOOP(Aptr, Btptr)                                           \
  const int tid = threadIdx.x;                                                \
  const int lane = tid & 63;                                                  \
  const int wv = tid >> 6;                                                    \
  const int wr = wv >> 1, wc = wv & 1;                                        \
  const int m0 = blockIdx.x * 128;                                            \
  const int n0 = blockIdx.y * 128;                                            \
  const int lr = lane & 15;                                                   \
  const int gq = lane >> 4;                                                   \
  const f32x4 fzero = {0.f, 0.f, 0.f, 0.f};                                   \
  f32x4 acc[4][4];                                                            \
  _Pragma("unroll") for (int i = 0; i < 4; ++i)                               \
      _Pragma("unroll") for (int j = 0; j < 4; ++j) acc[i][j] = fzero;        \
  {                                                                           \
    const int chunk0 = tid, chunk1 = tid + 256;                               \
    const int ar0 = chunk0 >> 2, ac0 = (chunk0 & 3) << 3;                     \
    const int ar1 = chunk1 >> 2, ac1 = (chunk1 & 3) << 3;                     \
    const int ub0 = (wv << 6) << 3;                                           \
    const int ub1 = (256 + (wv << 6)) << 3;                                   \
    for (int k0 = 0; k0 < KDIM; k0 += 32) {                                   \
      gload16(&(Aptr)[(size_t)(m0 + ar0) * KDIM + k0 + ac0],                  \
              &lds_a[0][0] + ub0);                                            \
      gload16(&(Aptr)[(size_t)(m0 + ar1) * KDIM + k0 + ac1],                  \
              &lds_a[0][0] + ub1);                                            \
      gload16(&(Btptr)[(size_t)(n0 + ar0) * KDIM + k0 + ac0],                 \
              &lds_b[0][0] + ub0);                                            \
      gload16(&(Btptr)[(size_t)(n0 + ar1) * KDIM + k0 + ac1],                 \
              &lds_b[0][0] + ub1);                                            \
      __syncthreads();                                                        \
      s16x8 af[4], bf[4];                                                     \
      _Pragma("unroll") for (int mi = 0; mi < 4; ++mi)                        \
          af[mi] = *reinterpret_cast<const s16x8*>(                           \
              &lds_a[wr * 64 + mi * 16 + lr][gq << 3]);                       \
      _Pragma("unroll") for (int ni = 0; ni < 4; ++ni)                        \
          bf[ni] = *reinterpret_cast<const s16x8*>(                           \
              &lds_b[wc * 64 + ni * 16 + lr][gq << 3]);                       \
      _Pragma("unroll") for (int ni = 0; ni < 4; ++ni)                        \
          _Pragma("unroll") for (int mi = 0; mi < 4; ++mi)                    \
              acc[mi][ni] = mfma16(af[mi], bf[ni], acc[mi][ni]);              \
      __syncthreads();                                                        \
    }                                                                         \
  }

// ---------------------------------------------------------------------------
// Kernel: qkv = Xbf @ Wt^T + b; route q/k/v.
// ---------------------------------------------------------------------------
__global__ __launch_bounds__(256) void qkv_gemm(
    const unsigned short* __restrict__ Xbf,  // [4096][1024] bf16
    const unsigned short* __restrict__ Wt,   // [3072][1024] bf16 (W^T)
    const float* __restrict__ Bias,          // [3072]
    float* out,                              // d_out
    unsigned short* __restrict__ Qbf)
{
  __shared__ __align__(16) unsigned short lds_a[128][32];
  __shared__ __align__(16) unsigned short lds_b[128][32];

  unsigned short* Kbf = (unsigned short*)out;   // a-slot scratch, 8 MiB
  unsigned short* Vt  = Kbf + 4194304;          // a-slot scratch, 8 MiB

  GEMM_MAIN_LOOP(Xbf, Wt)

#pragma unroll
  for (int ni = 0; ni < 4; ++ni) {
    int c = n0 + wc * 64 + ni * 16 + lr;
    float bias = Bias[c];
    int seg = c >> 10;          // 0=q 1=k 2=v  (wave-uniform per ni)
    int cc = c & 1023;
    int h = cc >> 6, d = cc & 63;
#pragma unroll
    for (int mi = 0; mi < 4; ++mi) {
#pragma unroll
      for (int j = 0; j < 4; ++j) {
        int m = m0 + wr * 64 + mi * 16 + gq * 4 + j;
        int b = m >> 11, s = m & 2047;
        float val = acc[mi][ni][j] + bias;
        size_t idx = (size_t)((b * NHEAD + h) * SEQ + s) * HDIM + d;
        if (seg == 0) {
          Qbf[idx] = f2bf(val * QSCALE);
        } else if (seg == 1) {
          out[OUT_K_BASE + idx] = val;
          Kbf[idx] = f2bf(val);
        } else {
          out[OUT_V_BASE + idx] = val;
          Vt[((size_t)(b * NHEAD + h) * HDIM + d) * SEQ + s] = f2bf(val);
        }
      }
    }
  }
}

// ---------------------------------------------------------------------------
// Kernel: out = Abf @ Wpt^T + b
// ---------------------------------------------------------------------------
__global__ __launch_bounds__(256) void proj_gemm(
    const unsigned short* __restrict__ Abf,  // [4096][1024] bf16
    const unsigned short* __restrict__ Wpt,  // [1024][1024] bf16 (W^T)
    const float* __restrict__ Bias,          // [1024]
    float* __restrict__ out)                 // [4096][1024] fp32
{
  __shared__ __align__(16) unsigned short lds_a[128][32];
  __shared__ __align__(16) unsigned short lds_b[128][32];

  GEMM_MAIN_LOOP(Abf, Wpt)

#pragma unroll
  for (int ni = 0; ni < 4; ++ni) {
    int c = n0 + wc * 64 + ni * 16 + lr;
    float bias = Bias[c];
#pragma unroll
    for (int mi = 0; mi < 4; ++mi) {
#pragma unroll
      for (int j = 0; j < 4; ++j) {
        int m = m0 + wr * 64 + mi * 16 + gq * 4 + j;
        out[(size_t)m * DMODEL + c] = acc[mi][ni][j] + bias;
      }
    }
  }
}

// ---------------------------------------------------------------------------
// Kernel: causal flash attention (unchanged from R2).
// Block = 64-row q-tile (4 waves x 16 rows). K/V double-buffered in LDS via
// global_load_lds with pre-swizzled source (chunk c of row r holds global
// chunk c^(r&7)) so all b128 fragment reads are bank-conflict-free.
// ---------------------------------------------------------------------------
__global__ __launch_bounds__(256, 4) void attn_fwd(
    const unsigned short* __restrict__ Qbf,  // pre-scaled bf16 [bh][s][d]
    const unsigned short* __restrict__ Kbf,  // bf16 [bh][s][d]
    const unsigned short* __restrict__ Vtg,  // bf16 [bh][d][s]
    unsigned short* __restrict__ Abf)        // bf16 [b][s][D] merged heads
{
  __shared__ __align__(16) unsigned short K_lds[2][64][64];
  __shared__ __align__(16) unsigned short V_lds[2][64][64];
  __shared__ __align__(16) unsigned short P_lds[4][16][64];

  const int tid = threadIdx.x;
  const int lane = tid & 63;
  const int wv = tid >> 6;
  const int bid = blockIdx.x;
  const int qt = 31 - (bid >> 5);   // longest blocks dispatch first (LPT)
  const int bh = bid & 31;

  const int lr = lane & 15;
  const int gq = lane >> 4;
  const int ks = gq << 3;

  const unsigned short* Kg = Kbf + (size_t)bh * (SEQ * HDIM);
  const unsigned short* Vg = Vtg + (size_t)bh * (SEQ * HDIM);
  const unsigned short* Qg = Qbf + (size_t)bh * (SEQ * HDIM)
                                 + (size_t)(qt * 64 + wv * 16) * HDIM;

  s16x8 qf0 = *reinterpret_cast<const s16x8*>(&Qg[lr * 64 + ks]);
  s16x8 qf1 = *reinterpret_cast<const s16x8*>(&Qg[lr * 64 + 32 + ks]);

  const f32x4 fzero = {0.f, 0.f, 0.f, 0.f};
  f32x4 O[4];
  float mrow[4], lrow[4];
#pragma unroll
  for (int j = 0; j < 4; ++j) { mrow[j] = -1e30f; lrow[j] = 0.f; O[j] = fzero; }

#define STAGE(kv0, nb)                                                        \
  {                                                                           \
    _Pragma("unroll")                                                         \
    for (int i = 0; i < 2; ++i) {                                             \
      int L = tid + (i << 8);                                                 \
      int r = L >> 3, c = L & 7;                                              \
      int cc = (c ^ (r & 7)) << 3;                                            \
      int ubase = ((i << 8) + (wv << 6)) << 3;                                \
      gload16(&Kg[(((kv0) + r) << 6) + cc], &K_lds[nb][0][0] + ubase);        \
      gload16(&Vg[((size_t)r << 11) + (kv0) + cc], &V_lds[nb][0][0] + ubase); \
    }                                                                         \
  }

  STAGE(0, 0);

  for (int t = 0; t <= qt; ++t) {
    __syncthreads();
    if (t < qt) STAGE((t + 1) * 64, (t + 1) & 1);
    const int buf = t & 1;

    // ---- S = Q K^T (pre-scaled, exp2 domain) ----
    f32x4 sc[4];
#pragma unroll
    for (int ni = 0; ni < 4; ++ni) {
      int kr = ni * 16 + lr;
      int sw = kr & 7;
      s16x8 kb0 = *reinterpret_cast<const s16x8*>(&K_lds[buf][kr][(gq ^ sw) << 3]);
      s16x8 kb1 = *reinterpret_cast<const s16x8*>(&K_lds[buf][kr][((gq + 4) ^ sw) << 3]);
      f32x4 tacc = mfma16(qf0, kb0, fzero);
      sc[ni] = mfma16(qf1, kb1, tacc);
    }

    if (t == qt) {
#pragma unroll
      for (int ni = 0; ni < 4; ++ni) {
        int cl = ni * 16 + lr;
#pragma unroll
        for (int j = 0; j < 4; ++j) {
          int rb = wv * 16 + gq * 4 + j;
          if (cl > rb) sc[ni][j] = -1e30f;
        }
      }
    }

    // ---- online softmax ----
#pragma unroll
    for (int j = 0; j < 4; ++j) {
      float tmax = fmaxf(fmaxf(sc[0][j], sc[1][j]), fmaxf(sc[2][j], sc[3][j]));
#pragma unroll
      for (int off = 1; off < 16; off <<= 1)
        tmax = fmaxf(tmax, __shfl_xor(tmax, off));
      float newm = fmaxf(mrow[j], tmax);
      float fs = __builtin_amdgcn_exp2f(mrow[j] - newm);
      mrow[j] = newm;
      float p0 = __builtin_amdgcn_exp2f(sc[0][j] - newm);
      float p1 = __builtin_amdgcn_exp2f(sc[1][j] - newm);
      float p2 = __builtin_amdgcn_exp2f(sc[2][j] - newm);
      float p3 = __builtin_amdgcn_exp2f(sc[3][j] - newm);
      float rs = (p0 + p1) + (p2 + p3);
#pragma unroll
      for (int off = 1; off < 16; off <<= 1)
        rs += __shfl_xor(rs, off);
      lrow[j] = lrow[j] * fs + rs;
#pragma unroll
      for (int ni = 0; ni < 4; ++ni) O[ni][j] *= fs;
      int rr = gq * 4 + j;
      int swp = rr & 7;
      P_lds[wv][rr][(((0 + (lr >> 3)) ^ swp) << 3) | (lr & 7)] = f2bf(p0);
      P_lds[wv][rr][(((2 + (lr >> 3)) ^ swp) << 3) | (lr & 7)] = f2bf(p1);
      P_lds[wv][rr][(((4 + (lr >> 3)) ^ swp) << 3) | (lr & 7)] = f2bf(p2);
      P_lds[wv][rr][(((6 + (lr >> 3)) ^ swp) << 3) | (lr & 7)] = f2bf(p3);
    }

    // ---- O += P V ----
    {
      int swl = lr & 7;
      s16x8 pf0 = *reinterpret_cast<const s16x8*>(&P_lds[wv][lr][(gq ^ swl) << 3]);
      s16x8 pf1 = *reinterpret_cast<const s16x8*>(&P_lds[wv][lr][((gq + 4) ^ swl) << 3]);
#pragma unroll
      for (int ni = 0; ni < 4; ++ni) {
        int dr = ni * 16 + lr;
        int sw = dr & 7;
        s16x8 vb0 = *reinterpret_cast<const s16x8*>(&V_lds[buf][dr][(gq ^ sw) << 3]);
        s16x8 vb1 = *reinterpret_cast<const s16x8*>(&V_lds[buf][dr][((gq + 4) ^ sw) << 3]);
        O[ni] = mfma16(pf0, vb0, O[ni]);
        O[ni] = mfma16(pf1, vb1, O[ni]);
      }
    }
  }

  const int b = bh >> 4, h = bh & 15;
#pragma unroll
  for (int j = 0; j < 4; ++j) {
    float inv = 1.0f / lrow[j];
    int s = qt * 64 + wv * 16 + gq * 4 + j;
#pragma unroll
    for (int ni = 0; ni < 4; ++ni) {
      Abf[(size_t)(b * SEQ + s) * DMODEL + h * 64 + ni * 16 + lr] =
          f2bf(O[ni][j] * inv);
    }
  }
#undef STAGE
}

// ---------------------------------------------------------------------------
extern "C" void kernel_launch(void* const* d_in, const int* in_sizes, int n_in,
                              void* d_out, int out_size, void* d_ws, size_t ws_size,
                              hipStream_t stream) {
  const float* x        = (const float*)d_in[0];
  const float* c_attn_w = (const float*)d_in[1];
  const float* c_attn_b = (const float*)d_in[2];
  const float* c_proj_w = (const float*)d_in[3];
  const float* c_proj_b = (const float*)d_in[4];
  float* out = (float*)d_out;

  // ws layout (ushort units):
  //  [0 .. 4M)   Qbf                       (8 MiB)
  //  [4M .. 8M)  Xbf (qkv) / Abf (attn+proj)  aliased by liveness (8 MiB)
  //  [8M .. 11M) Wt (qkv) / Wpt (proj)        aliased by liveness (6 MiB)
  unsigned short* Qbf = (unsigned short*)d_ws;
  unsigned short* Xbf = Qbf + 4194304;
  unsigned short* Abf = Xbf;                 // alias: Xbf dead after qkv
  unsigned short* Wt  = Qbf + 8388608;
  unsigned short* Wpt = Wt;                  // alias: Wt dead after qkv
  unsigned short* Kbf = (unsigned short*)out;  // a-slot scratch
  unsigned short* Vt  = Kbf + 4194304;

  convert_x<<<dim3(4096), 256, 0, stream>>>(x, Xbf);
  convert_wt<<<dim3(48, 16), 256, 0, stream>>>(c_attn_w, Wt, NQKV);
  qkv_gemm<<<dim3(32, 24), 256, 0, stream>>>(Xbf, Wt, c_attn_b, out, Qbf);
  convert_wt<<<dim3(16, 16), 256, 0, stream>>>(c_proj_w, Wpt, DMODEL);
  attn_fwd<<<dim3(1024), 256, 0, stream>>>(Qbf, Kbf, Vt, Abf);
  proj_gemm<<<dim3(32, 8), 256, 0, stream>>>(Abf, Wpt, c_proj_b, out);
}

// Round 4
// 132.894 us; speedup vs baseline: 2.9088x; 1.0838x over previous
//
#include <hip/hip_runtime.h>
#include <hip/hip_bf16.h>
#include <cstdint>
#include <cstddef>

// Problem dims
#define SEQ 2048
#define DMODEL 1024
#define NHEAD 16
#define HDIM 64
#define MTOT 4096      // B*S
#define NQKV 3072
#define KDIM 1024

// d_out layout (floats): a[4194304] | k[4194304] | v[4194304]
#define OUT_K_BASE  4194304u
#define OUT_V_BASE  8388608u

// 0.125 * log2(e): folded into Q so QK^T scores are already in exp2 domain
#define QSCALE 0.18033688011112043f

typedef __attribute__((ext_vector_type(4))) float f32x4;
typedef __attribute__((ext_vector_type(8))) __bf16 bf16x8;
typedef __attribute__((ext_vector_type(8))) short s16x8;
typedef __attribute__((ext_vector_type(4))) short s16x4;
typedef __attribute__((ext_vector_type(4))) int i32x4;

static __device__ __forceinline__ unsigned short f2bf(float f) {
  unsigned int u = __builtin_bit_cast(unsigned int, f);
  u += 0x7FFFu + ((u >> 16) & 1u);
  return (unsigned short)(u >> 16);
}

static __device__ __forceinline__ s16x4 pack4(float4 v) {
  s16x4 r;
  r[0] = (short)f2bf(v.x);
  r[1] = (short)f2bf(v.y);
  r[2] = (short)f2bf(v.z);
  r[3] = (short)f2bf(v.w);
  return r;
}

// packed 2x f32 -> 2x bf16 in one dword (elem0 = lo)
static __device__ __forceinline__ int cvtpk(float lo, float hi) {
  int r;
  asm("v_cvt_pk_bf16_f32 %0, %1, %2" : "=v"(r) : "v"(lo), "v"(hi));
  return r;
}

static __device__ __forceinline__ f32x4 mfma16(s16x8 a, s16x8 b, f32x4 c) {
  return __builtin_amdgcn_mfma_f32_16x16x32_bf16(
      __builtin_bit_cast(bf16x8, a), __builtin_bit_cast(bf16x8, b), c, 0, 0, 0);
}

// async global->LDS, 16B per lane. LDS dest: wave-uniform base + lane*16.
static __device__ __forceinline__ void gload16(const void* g, void* l) {
  __builtin_amdgcn_global_load_lds(
      (const __attribute__((address_space(1))) unsigned int*)(uintptr_t)g,
      (__attribute__((address_space(3))) unsigned int*)(uintptr_t)l,
      16, 0, 0);
}

// ---------------------------------------------------------------------------
// Pre-pass: X (fp32 [4096][1024]) -> Xbf (bf16, same layout)
// ---------------------------------------------------------------------------
__global__ __launch_bounds__(256) void convert_x(
    const float* __restrict__ X, unsigned short* __restrict__ Xbf)
{
  int i = blockIdx.x * 256 + threadIdx.x;   // float4 index, 1M total
  float4 v = reinterpret_cast<const float4*>(X)[i];
  reinterpret_cast<s16x4*>(Xbf)[i] = pack4(v);
}

// ---------------------------------------------------------------------------
// Pre-pass: W (fp32 [1024][N]) -> Wt (bf16 [N][1024]) tiled transpose via LDS
// grid = (N/64, 16)
// ---------------------------------------------------------------------------
__global__ __launch_bounds__(256) void convert_wt(
    const float* __restrict__ W, unsigned short* __restrict__ Wt, int N)
{
  __shared__ unsigned short t[64][72];
  const int n0 = blockIdx.x * 64, k0 = blockIdx.y * 64;
  const int tid = threadIdx.x;
#pragma unroll
  for (int i = 0; i < 4; ++i) {
    int f = tid + (i << 8);
    int r = f >> 4, c4 = (f & 15) << 2;
    float4 v = *reinterpret_cast<const float4*>(&W[(size_t)(k0 + r) * N + n0 + c4]);
    *reinterpret_cast<s16x4*>(&t[r][c4]) = pack4(v);
  }
  __syncthreads();
#pragma unroll
  for (int i = 0; i < 2; ++i) {
    int g = tid + (i << 8);
    int n = g >> 3, k8 = (g & 7) << 3;
    s16x8 o;
#pragma unroll
    for (int jj = 0; jj < 8; ++jj) o[jj] = (short)t[k8 + jj][n];
    *reinterpret_cast<s16x8*>(&Wt[(size_t)(n0 + n) * KDIM + k0 + k8]) = o;
  }
}

// ---------------------------------------------------------------------------
// 2-phase double-buffered GEMM main loop (T3-minimum recipe).
// A: bf16 [M][1024] row-major; Bt: bf16 [N][1024] row-major (= B transposed).
// 128x128 tile, 4 waves (2x2 of 64x64), BK=32. STAGE for step t+1 is issued
// right after the barrier; its vmcnt drains at the NEXT barrier, so loads
// have a full ds_read+MFMA phase in flight.
// ---------------------------------------------------------------------------
#define GEMM_MAIN_LOOP(Aptr, Btptr)                                           \
  const int tid = threadIdx.x;                                                \
  const int lane = tid & 63;                                                  \
  const int wv = tid >> 6;                                                    \
  const int wr = wv >> 1, wc = wv & 1;                                        \
  const int m0 = blockIdx.x * 128;                                            \
  const int n0 = blockIdx.y * 128;                                            \
  const int lr = lane & 15;                                                   \
  const int gq = lane >> 4;                                                   \
  const f32x4 fzero = {0.f, 0.f, 0.f, 0.f};                                   \
  f32x4 acc[4][4];                                                            \
  _Pragma("unroll") for (int i = 0; i < 4; ++i)                               \
      _Pragma("unroll") for (int j = 0; j < 4; ++j) acc[i][j] = fzero;        \
  {                                                                           \
    const int ar0 = tid >> 2, ac0 = (tid & 3) << 3;                           \
    const int ar1 = (tid + 256) >> 2, ac1 = (tid & 3) << 3;                   \
    const int ub0 = wv << 9;                                                  \
    const int ub1 = 2048 + (wv << 9);                                         \
    /* stage buffer nb with K-offset kk */                                    \
    auto stage = [&](int nb, int kk) {                                        \
      gload16(&(Aptr)[(size_t)(m0 + ar0) * KDIM + kk + ac0],                  \
              &lds_a[nb][0][0] + ub0);                                        \
      gload16(&(Aptr)[(size_t)(m0 + ar1) * KDIM + kk + ac1],                  \
              &lds_a[nb][0][0] + ub1);                                        \
      gload16(&(Btptr)[(size_t)(n0 + ar0) * KDIM + kk + ac0],                 \
              &lds_b[nb][0][0] + ub0);                                        \
      gload16(&(Btptr)[(size_t)(n0 + ar1) * KDIM + kk + ac1],                 \
              &lds_b[nb][0][0] + ub1);                                        \
    };                                                                        \
    stage(0, 0);                                                              \
    for (int t = 0; t < 32; ++t) {                                            \
      __syncthreads(); /* buf[t&1] staged (vmcnt drained here) */             \
      if (t < 31) stage((t + 1) & 1, (t + 1) << 5);                           \
      const int bufg = t & 1;                                                 \
      s16x8 af[4], bfv[4];                                                    \
      _Pragma("unroll") for (int mi = 0; mi < 4; ++mi)                        \
          af[mi] = *reinterpret_cast<const s16x8*>(                           \
              &lds_a[bufg][wr * 64 + mi * 16 + lr][gq << 3]);                 \
      _Pragma("unroll") for (int ni = 0; ni < 4; ++ni)                        \
          bfv[ni] = *reinterpret_cast<const s16x8*>(                          \
              &lds_b[bufg][wc * 64 + ni * 16 + lr][gq << 3]);                 \
      _Pragma("unroll") for (int ni = 0; ni < 4; ++ni)                        \
          _Pragma("unroll") for (int mi = 0; mi < 4; ++mi)                    \
              acc[mi][ni] = mfma16(af[mi], bfv[ni], acc[mi][ni]);             \
    }                                                                         \
  }

// ---------------------------------------------------------------------------
// Kernel: qkv = Xbf @ Wt^T + b; route q/k/v.
// ---------------------------------------------------------------------------
__global__ __launch_bounds__(256) void qkv_gemm(
    const unsigned short* __restrict__ Xbf,  // [4096][1024] bf16
    const unsigned short* __restrict__ Wt,   // [3072][1024] bf16 (W^T)
    const float* __restrict__ Bias,          // [3072]
    float* out,                              // d_out
    unsigned short* __restrict__ Qbf)
{
  __shared__ __align__(16) unsigned short lds_a[2][128][32];
  __shared__ __align__(16) unsigned short lds_b[2][128][32];

  unsigned short* Kbf = (unsigned short*)out;   // a-slot scratch, 8 MiB
  unsigned short* Vt  = Kbf + 4194304;          // a-slot scratch, 8 MiB

  GEMM_MAIN_LOOP(Xbf, Wt)

#pragma unroll
  for (int ni = 0; ni < 4; ++ni) {
    int c = n0 + wc * 64 + ni * 16 + lr;
    float bias = Bias[c];
    int seg = c >> 10;          // 0=q 1=k 2=v
    int cc = c & 1023;
    int h = cc >> 6, d = cc & 63;
#pragma unroll
    for (int mi = 0; mi < 4; ++mi) {
#pragma unroll
      for (int j = 0; j < 4; ++j) {
        int m = m0 + wr * 64 + mi * 16 + gq * 4 + j;
        int b = m >> 11, s = m & 2047;
        float val = acc[mi][ni][j] + bias;
        size_t idx = (size_t)((b * NHEAD + h) * SEQ + s) * HDIM + d;
        if (seg == 0) {
          Qbf[idx] = f2bf(val * QSCALE);
        } else if (seg == 1) {
          out[OUT_K_BASE + idx] = val;
          Kbf[idx] = f2bf(val);
        } else {
          out[OUT_V_BASE + idx] = val;
          Vt[((size_t)(b * NHEAD + h) * HDIM + d) * SEQ + s] = f2bf(val);
        }
      }
    }
  }
}

// ---------------------------------------------------------------------------
// Kernel: out = Abf @ Wpt^T + b
// ---------------------------------------------------------------------------
__global__ __launch_bounds__(256) void proj_gemm(
    const unsigned short* __restrict__ Abf,  // [4096][1024] bf16
    const unsigned short* __restrict__ Wpt,  // [1024][1024] bf16 (W^T)
    const float* __restrict__ Bias,          // [1024]
    float* __restrict__ out)                 // [4096][1024] fp32
{
  __shared__ __align__(16) unsigned short lds_a[2][128][32];
  __shared__ __align__(16) unsigned short lds_b[2][128][32];

  GEMM_MAIN_LOOP(Abf, Wpt)

#pragma unroll
  for (int ni = 0; ni < 4; ++ni) {
    int c = n0 + wc * 64 + ni * 16 + lr;
    float bias = Bias[c];
#pragma unroll
    for (int mi = 0; mi < 4; ++mi) {
#pragma unroll
      for (int j = 0; j < 4; ++j) {
        int m = m0 + wr * 64 + mi * 16 + gq * 4 + j;
        out[(size_t)m * DMODEL + c] = acc[mi][ni][j] + bias;
      }
    }
  }
}

// ---------------------------------------------------------------------------
// Kernel: causal flash attention — swapped QK^T, in-register softmax.
// Block = 64-row q-tile (4 waves x 16 rows). Each lane owns q = lane&15;
// S^T = mfma(K, Q) puts 16 kv-scores for that q in-lane (kv = 16ni+4gq+reg).
// P is repacked to PV B-frags via cvt_pk + bpermute; O accumulates
// transposed (O^T[d][q], q = lane&15) so m/l/fs stay lane-local.
// ---------------------------------------------------------------------------
__global__ __launch_bounds__(256) void attn_fwd(
    const unsigned short* __restrict__ Qbf,  // pre-scaled bf16 [bh][s][d]
    const unsigned short* __restrict__ Kbf,  // bf16 [bh][s][d]
    const unsigned short* __restrict__ Vtg,  // bf16 [bh][d][s]
    unsigned short* __restrict__ Abf)        // bf16 [b][s][D] merged heads
{
  __shared__ __align__(16) unsigned short K_lds[2][64][64];
  __shared__ __align__(16) unsigned short V_lds[2][64][64];

  const int tid = threadIdx.x;
  const int lane = tid & 63;
  const int wv = tid >> 6;
  const int bid = blockIdx.x;
  const int qt = 31 - (bid >> 5);   // longest blocks dispatch first (LPT)
  const int bh = bid & 31;

  const int lr = lane & 15;
  const int gq = lane >> 4;

  const unsigned short* Kg = Kbf + (size_t)bh * (SEQ * HDIM);
  const unsigned short* Vg = Vtg + (size_t)bh * (SEQ * HDIM);
  const unsigned short* Qg = Qbf + (size_t)bh * (SEQ * HDIM)
                                 + (size_t)(qt * 64 + wv * 16) * HDIM;

  // Q B-frags: col=q=lr, k=d. qf0: d=8gq+j, qf1: d=32+8gq+j.
  s16x8 qf0 = *reinterpret_cast<const s16x8*>(&Qg[lr * 64 + (gq << 3)]);
  s16x8 qf1 = *reinterpret_cast<const s16x8*>(&Qg[lr * 64 + 32 + (gq << 3)]);

  const f32x4 fzero = {0.f, 0.f, 0.f, 0.f};
  f32x4 O[4];      // O^T tile ni: d = 16ni+4gq+reg, q = lr
  float mrow = -1e30f, lrow = 0.f;
#pragma unroll
  for (int ni = 0; ni < 4; ++ni) O[ni] = fzero;

#define STAGE(kv0, nb)                                                        \
  {                                                                           \
    _Pragma("unroll")                                                         \
    for (int i = 0; i < 2; ++i) {                                             \
      int L = tid + (i << 8);                                                 \
      int r = L >> 3, c = L & 7;                                              \
      int cc = (c ^ (r & 7)) << 3;                                            \
      int ubase = ((i << 8) + (wv << 6)) << 3;                                \
      gload16(&Kg[(((kv0) + r) << 6) + cc], &K_lds[nb][0][0] + ubase);        \
      gload16(&Vg[((size_t)r << 11) + (kv0) + cc], &V_lds[nb][0][0] + ubase); \
    }                                                                         \
  }

  STAGE(0, 0);

  for (int t = 0; t <= qt; ++t) {
    __syncthreads();
    if (t < qt) STAGE((t + 1) * 64, (t + 1) & 1);
    const int buf = t & 1;

    // ---- S^T = K Q^T : sc[ni][reg] = S[q=lr][kv=16ni+4gq+reg] ----
    f32x4 sc[4];
#pragma unroll
    for (int ni = 0; ni < 4; ++ni) {
      int kr = ni * 16 + lr;
      int sw = kr & 7;
      s16x8 kb0 = *reinterpret_cast<const s16x8*>(&K_lds[buf][kr][(gq ^ sw) << 3]);
      s16x8 kb1 = *reinterpret_cast<const s16x8*>(&K_lds[buf][kr][((gq + 4) ^ sw) << 3]);
      f32x4 tacc = mfma16(kb0, qf0, fzero);
      sc[ni] = mfma16(kb1, qf1, tacc);
    }

    // ---- causal mask (diag tile only): kv_local > q_local ----
    if (t == qt) {
      int qloc = wv * 16 + lr;
#pragma unroll
      for (int ni = 0; ni < 4; ++ni)
#pragma unroll
        for (int r = 0; r < 4; ++r)
          if (ni * 16 + gq * 4 + r > qloc) sc[ni][r] = -1e30f;
    }

    // ---- in-register online softmax (q = lr, 16 scores in-lane) ----
    float tmax = fmaxf(fmaxf(fmaxf(sc[0][0], sc[0][1]), fmaxf(sc[0][2], sc[0][3])),
                       fmaxf(fmaxf(sc[1][0], sc[1][1]), fmaxf(sc[1][2], sc[1][3])));
    tmax = fmaxf(tmax,
                 fmaxf(fmaxf(fmaxf(sc[2][0], sc[2][1]), fmaxf(sc[2][2], sc[2][3])),
                       fmaxf(fmaxf(sc[3][0], sc[3][1]), fmaxf(sc[3][2], sc[3][3]))));
    tmax = fmaxf(tmax, __shfl_xor(tmax, 16));
    tmax = fmaxf(tmax, __shfl_xor(tmax, 32));
    float newm = fmaxf(mrow, tmax);
    float fs = __builtin_amdgcn_exp2f(mrow - newm);
    mrow = newm;
    float rs = 0.f;
#pragma unroll
    for (int ni = 0; ni < 4; ++ni) {
#pragma unroll
      for (int r = 0; r < 4; ++r) {
        float p = __builtin_amdgcn_exp2f(sc[ni][r] - newm);
        sc[ni][r] = p;
        rs += p;
      }
    }
    rs += __shfl_xor(rs, 16);
    rs += __shfl_xor(rs, 32);
    lrow = lrow * fs + rs;
#pragma unroll
    for (int ni = 0; ni < 4; ++ni) O[ni] *= fs;

    // ---- repack P -> PV B-frags (P^T: col=q=lr, k=kv) ----
    // pk[ni][r2] = bf16 pair (kv = 16ni+4gq+2r2, +1)
    int pk[4][2];
#pragma unroll
    for (int ni = 0; ni < 4; ++ni) {
      pk[ni][0] = cvtpk(sc[ni][0], sc[ni][1]);
      pk[ni][1] = cvtpk(sc[ni][2], sc[ni][3]);
    }
    // B-frag half h, dword t holds kv pair (32h+8gq+2t, +1), pulled from
    // lane (lr, gq_src = 2(gq&1)+(t>>1)), reg pk[2h+(gq>>1)][t&1].
    const int srcA = lr + ((lane & 16) << 1);        // 16 * (2*(gq&1))
    const int srcB = srcA + 16;
    const bool lowhalf = (gq < 2);
    s16x8 pB[2];
#pragma unroll
    for (int h = 0; h < 2; ++h) {
      int y0 = __shfl(pk[2 * h][0], srcA);
      int y1 = __shfl(pk[2 * h][1], srcA);
      int y2 = __shfl(pk[2 * h][0], srcB);
      int y3 = __shfl(pk[2 * h][1], srcB);
      int z0 = __shfl(pk[2 * h + 1][0], srcA);
      int z1 = __shfl(pk[2 * h + 1][1], srcA);
      int z2 = __shfl(pk[2 * h + 1][0], srcB);
      int z3 = __shfl(pk[2 * h + 1][1], srcB);
      i32x4 dw;
      dw[0] = lowhalf ? y0 : z0;
      dw[1] = lowhalf ? y1 : z1;
      dw[2] = lowhalf ? y2 : z2;
      dw[3] = lowhalf ? y3 : z3;
      pB[h] = __builtin_bit_cast(s16x8, dw);
    }

    // ---- O^T += V^T P^T : A = V^T tile (row=d=16ni+lr, k=kv) ----
#pragma unroll
    for (int ni = 0; ni < 4; ++ni) {
      int dr = ni * 16 + lr;
      int sw = dr & 7;
      s16x8 vb0 = *reinterpret_cast<const s16x8*>(&V_lds[buf][dr][(gq ^ sw) << 3]);
      s16x8 vb1 = *reinterpret_cast<const s16x8*>(&V_lds[buf][dr][((gq + 4) ^ sw) << 3]);
      O[ni] = mfma16(vb0, pB[0], O[ni]);
      O[ni] = mfma16(vb1, pB[1], O[ni]);
    }
  }

  // ---- normalize + write merged heads (bf16); lane owns q=lr ----
  const int b = bh >> 4, h = bh & 15;
  float inv = 1.0f / lrow;
  int srow = qt * 64 + wv * 16 + lr;
  size_t base = (size_t)(b * SEQ + srow) * DMODEL + h * 64 + (gq << 2);
#pragma unroll
  for (int ni = 0; ni < 4; ++ni) {
    s16x4 ov;
#pragma unroll
    for (int r = 0; r < 4; ++r) ov[r] = (short)f2bf(O[ni][r] * inv);
    *reinterpret_cast<s16x4*>(&Abf[base + ni * 16]) = ov;
  }
#undef STAGE
}

// ---------------------------------------------------------------------------
extern "C" void kernel_launch(void* const* d_in, const int* in_sizes, int n_in,
                              void* d_out, int out_size, void* d_ws, size_t ws_size,
                              hipStream_t stream) {
  const float* x        = (const float*)d_in[0];
  const float* c_attn_w = (const float*)d_in[1];
  const float* c_attn_b = (const float*)d_in[2];
  const float* c_proj_w = (const float*)d_in[3];
  const float* c_proj_b = (const float*)d_in[4];
  float* out = (float*)d_out;

  // ws layout (ushort units):
  //  [0 .. 4M)   Qbf
  //  [4M .. 8M)  Xbf (qkv) / Abf (attn+proj)  aliased by liveness
  //  [8M .. 11M) Wt (qkv) / Wpt (proj)        aliased by liveness
  unsigned short* Qbf = (unsigned short*)d_ws;
  unsigned short* Xbf = Qbf + 4194304;
  unsigned short* Abf = Xbf;
  unsigned short* Wt  = Qbf + 8388608;
  unsigned short* Wpt = Wt;
  unsigned short* Kbf = (unsigned short*)out;  // a-slot scratch
  unsigned short* Vt  = Kbf + 4194304;

  convert_x<<<dim3(4096), 256, 0, stream>>>(x, Xbf);
  convert_wt<<<dim3(48, 16), 256, 0, stream>>>(c_attn_w, Wt, NQKV);
  qkv_gemm<<<dim3(32, 24), 256, 0, stream>>>(Xbf, Wt, c_attn_b, out, Qbf);
  convert_wt<<<dim3(16, 16), 256, 0, stream>>>(c_proj_w, Wpt, DMODEL);
  attn_fwd<<<dim3(1024), 256, 0, stream>>>(Qbf, Kbf, Vt, Abf);
  proj_gemm<<<dim3(32, 8), 256, 0, stream>>>(Abf, Wpt, c_proj_b, out);
}

// Round 6
// 120.289 us; speedup vs baseline: 3.2137x; 1.1048x over previous
//
#include <hip/hip_runtime.h>
#include <hip/hip_bf16.h>
#include <cstdint>
#include <cstddef>

// Problem dims
#define SEQ 2048
#define DMODEL 1024
#define NHEAD 16
#define HDIM 64
#define MTOT 4096      // B*S
#define NQKV 3072
#define KDIM 1024

// d_out layout (floats): a[4194304] | k[4194304] | v[4194304]
#define OUT_K_BASE  4194304u
#define OUT_V_BASE  8388608u

// 0.125 * log2(e): folded into Q so QK^T scores are already in exp2 domain
#define QSCALE 0.18033688011112043f

typedef __attribute__((ext_vector_type(4))) float f32x4;
typedef __attribute__((ext_vector_type(8))) __bf16 bf16x8;
typedef __attribute__((ext_vector_type(8))) short s16x8;
typedef __attribute__((ext_vector_type(4))) short s16x4;
typedef __attribute__((ext_vector_type(2))) int i32x2;

static __device__ __forceinline__ unsigned short f2bf(float f) {
  unsigned int u = __builtin_bit_cast(unsigned int, f);
  u += 0x7FFFu + ((u >> 16) & 1u);
  return (unsigned short)(u >> 16);
}

static __device__ __forceinline__ s16x4 pack4(float4 v) {
  s16x4 r;
  r[0] = (short)f2bf(v.x);
  r[1] = (short)f2bf(v.y);
  r[2] = (short)f2bf(v.z);
  r[3] = (short)f2bf(v.w);
  return r;
}

// packed 2x f32 -> 2x bf16 in one dword (elem0 = lo)
static __device__ __forceinline__ int cvtpk(float lo, float hi) {
  int r;
  asm("v_cvt_pk_bf16_f32 %0, %1, %2" : "=v"(r) : "v"(lo), "v"(hi));
  return r;
}

static __device__ __forceinline__ f32x4 mfma16(s16x8 a, s16x8 b, f32x4 c) {
  return __builtin_amdgcn_mfma_f32_16x16x32_bf16(
      __builtin_bit_cast(bf16x8, a), __builtin_bit_cast(bf16x8, b), c, 0, 0, 0);
}

// async global->LDS, 16B per lane. LDS dest: wave-uniform base + lane*16.
static __device__ __forceinline__ void gload16(const void* g, void* l) {
  __builtin_amdgcn_global_load_lds(
      (const __attribute__((address_space(1))) unsigned int*)(uintptr_t)g,
      (__attribute__((address_space(3))) unsigned int*)(uintptr_t)l,
      16, 0, 0);
}

// ---------------------------------------------------------------------------
// Pre-pass: X (fp32 [4096][1024]) -> Xbf (bf16, same layout)
// ---------------------------------------------------------------------------
__global__ __launch_bounds__(256) void convert_x(
    const float* __restrict__ X, unsigned short* __restrict__ Xbf)
{
  int i = blockIdx.x * 256 + threadIdx.x;   // float4 index, 1M total
  float4 v = reinterpret_cast<const float4*>(X)[i];
  reinterpret_cast<s16x4*>(Xbf)[i] = pack4(v);
}

// ---------------------------------------------------------------------------
// Pre-pass: W (fp32 [1024][N]) -> Wt (bf16 [N][1024]) tiled transpose via LDS
// grid = (N/64, 16)
// ---------------------------------------------------------------------------
__global__ __launch_bounds__(256) void convert_wt(
    const float* __restrict__ W, unsigned short* __restrict__ Wt, int N)
{
  __shared__ unsigned short t[64][72];
  const int n0 = blockIdx.x * 64, k0 = blockIdx.y * 64;
  const int tid = threadIdx.x;
#pragma unroll
  for (int i = 0; i < 4; ++i) {
    int f = tid + (i << 8);
    int r = f >> 4, c4 = (f & 15) << 2;
    float4 v = *reinterpret_cast<const float4*>(&W[(size_t)(k0 + r) * N + n0 + c4]);
    *reinterpret_cast<s16x4*>(&t[r][c4]) = pack4(v);
  }
  __syncthreads();
#pragma unroll
  for (int i = 0; i < 2; ++i) {
    int g = tid + (i << 8);
    int n = g >> 3, k8 = (g & 7) << 3;
    s16x8 o;
#pragma unroll
    for (int jj = 0; jj < 8; ++jj) o[jj] = (short)t[k8 + jj][n];
    *reinterpret_cast<s16x8*>(&Wt[(size_t)(n0 + n) * KDIM + k0 + k8]) = o;
  }
}

// ---------------------------------------------------------------------------
// 2-phase double-buffered GEMM main loop.
// LDS tiles are [128][32] ushort (64B rows = 4 16B chunks). Chunk index is
// XOR-swizzled with ((row>>1)&3); staged via inverse-swizzled GLOBAL source
// (gload_lds dest linear), read back with the same XOR (rule #21).
// ---------------------------------------------------------------------------
#define GEMM_MAIN_LOOP(Aptr, Btptr)                                           \
  const int tid = threadIdx.x;                                                \
  const int lane = tid & 63;                                                  \
  const int wv = tid >> 6;                                                    \
  const int wr = wv >> 1, wc = wv & 1;                                        \
  const int m0 = blockIdx.x * 128;                                            \
  const int n0 = blockIdx.y * 128;                                            \
  const int lr = lane & 15;                                                   \
  const int gq = lane >> 4;                                                   \
  const f32x4 fzero = {0.f, 0.f, 0.f, 0.f};                                   \
  f32x4 acc[4][4];                                                            \
  _Pragma("unroll") for (int i = 0; i < 4; ++i)                               \
      _Pragma("unroll") for (int j = 0; j < 4; ++j) acc[i][j] = fzero;        \
  {                                                                           \
    const int ar0 = tid >> 2;                                                 \
    const int ar1 = ar0 + 64;                                                 \
    const int ac0 = (((tid & 3) ^ ((ar0 >> 1) & 3)) << 3);                    \
    const int ub0 = wv << 9;                                                  \
    const int ub1 = 2048 + (wv << 9);                                         \
    auto stage = [&](int nb, int kk) {                                        \
      gload16(&(Aptr)[(size_t)(m0 + ar0) * KDIM + kk + ac0],                  \
              &lds_a[nb][0][0] + ub0);                                        \
      gload16(&(Aptr)[(size_t)(m0 + ar1) * KDIM + kk + ac0],                  \
              &lds_a[nb][0][0] + ub1);                                        \
      gload16(&(Btptr)[(size_t)(n0 + ar0) * KDIM + kk + ac0],                 \
              &lds_b[nb][0][0] + ub0);                                        \
      gload16(&(Btptr)[(size_t)(n0 + ar1) * KDIM + kk + ac0],                 \
              &lds_b[nb][0][0] + ub1);                                        \
    };                                                                        \
    stage(0, 0);                                                              \
    const int fsw = ((lr >> 1) & 3);                                          \
    for (int t = 0; t < 32; ++t) {                                            \
      __syncthreads(); /* buf[t&1] staged (vmcnt drained here) */             \
      if (t < 31) stage((t + 1) & 1, (t + 1) << 5);                           \
      const int bufg = t & 1;                                                 \
      s16x8 af[4], bfv[4];                                                    \
      _Pragma("unroll") for (int mi = 0; mi < 4; ++mi)                        \
          af[mi] = *reinterpret_cast<const s16x8*>(                           \
              &lds_a[bufg][wr * 64 + mi * 16 + lr][(gq ^ fsw) << 3]);         \
      _Pragma("unroll") for (int ni = 0; ni < 4; ++ni)                        \
          bfv[ni] = *reinterpret_cast<const s16x8*>(                          \
              &lds_b[bufg][wc * 64 + ni * 16 + lr][(gq ^ fsw) << 3]);         \
      _Pragma("unroll") for (int ni = 0; ni < 4; ++ni)                        \
          _Pragma("unroll") for (int mi = 0; mi < 4; ++mi)                    \
              acc[mi][ni] = mfma16(af[mi], bfv[ni], acc[mi][ni]);             \
    }                                                                         \
  }

// ---------------------------------------------------------------------------
// Kernel: qkv = Xbf @ Wt^T + b; route q/k/v. seg is block-uniform.
// ---------------------------------------------------------------------------
__global__ __launch_bounds__(256) void qkv_gemm(
    const unsigned short* __restrict__ Xbf,  // [4096][1024] bf16
    const unsigned short* __restrict__ Wt,   // [3072][1024] bf16 (W^T)
    const float* __restrict__ Bias,          // [3072]
    float* out,                              // d_out
    unsigned short* __restrict__ Qbf)
{
  __shared__ __align__(16) unsigned short lds_a[2][128][32];
  __shared__ __align__(16) unsigned short lds_b[2][128][32];

  unsigned short* Kbf = (unsigned short*)out;   // a-slot scratch, 8 MiB
  unsigned short* Vt  = Kbf + 4194304;          // a-slot scratch, 8 MiB

  GEMM_MAIN_LOOP(Xbf, Wt)

  const int seg = n0 >> 10;   // 0=q 1=k 2=v (block-uniform)

  if (seg == 0) {
#pragma unroll
    for (int ni = 0; ni < 4; ++ni) {
      int c = n0 + wc * 64 + ni * 16 + lr;
      float bias = Bias[c];
      int h = (c & 1023) >> 6, d = c & 63;
#pragma unroll
      for (int mi = 0; mi < 4; ++mi)
#pragma unroll
        for (int j = 0; j < 4; ++j) {
          int m = m0 + wr * 64 + mi * 16 + gq * 4 + j;
          int b = m >> 11, s = m & 2047;
          Qbf[(size_t)((b * NHEAD + h) * SEQ + s) * HDIM + d] =
              f2bf((acc[mi][ni][j] + bias) * QSCALE);
        }
    }
  } else if (seg == 1) {
#pragma unroll
    for (int ni = 0; ni < 4; ++ni) {
      int c = n0 + wc * 64 + ni * 16 + lr;
      float bias = Bias[c];
      int h = (c & 1023) >> 6, d = c & 63;
#pragma unroll
      for (int mi = 0; mi < 4; ++mi)
#pragma unroll
        for (int j = 0; j < 4; ++j) {
          int m = m0 + wr * 64 + mi * 16 + gq * 4 + j;
          int b = m >> 11, s = m & 2047;
          float val = acc[mi][ni][j] + bias;
          size_t idx = (size_t)((b * NHEAD + h) * SEQ + s) * HDIM + d;
          out[OUT_K_BASE + idx] = val;
          Kbf[idx] = f2bf(val);
        }
    }
  } else {
    // V block: fp32 present store + LDS-transposed coalesced Vt store.
    __syncthreads();   // main-loop LDS reads done in all waves before reuse
    unsigned short* T = (wv < 2) ? (&lds_a[0][0][0] + (wv << 12))
                                 : (&lds_b[0][0][0] + ((wv - 2) << 12));
    const int b = m0 >> 11;
    const int s0 = (m0 & 2047) + wr * 64;
    const int h = (n0 >> 6) - 32 + wc;
#pragma unroll
    for (int ni = 0; ni < 4; ++ni) {
      int c = n0 + wc * 64 + ni * 16 + lr;
      float bias = Bias[c];
      int d_loc = ni * 16 + lr;
      int dsw = d_loc & 7;
#pragma unroll
      for (int mi = 0; mi < 4; ++mi)
#pragma unroll
        for (int j = 0; j < 4; ++j) {
          int s_loc = mi * 16 + gq * 4 + j;
          float val = acc[mi][ni][j] + bias;
          out[OUT_V_BASE +
              (size_t)((b * NHEAD + h) * SEQ + s0 + s_loc) * HDIM + d_loc] = val;
          T[d_loc * 64 + ((((s_loc >> 3) ^ dsw)) << 3) + (s_loc & 7)] = f2bf(val);
        }
    }
    // read back transposed (8 rows x 8 chunks per iteration, coalesced stores)
#pragma unroll
    for (int it = 0; it < 8; ++it) {
      int dl = (lane >> 3) + (it << 3);
      int cl = lane & 7;
      s16x8 vv = *reinterpret_cast<const s16x8*>(
          &T[dl * 64 + ((cl ^ (dl & 7)) << 3)]);
      size_t vi = (((size_t)(b * NHEAD + h) * HDIM + dl) << 11) + s0 + (cl << 3);
      *reinterpret_cast<s16x8*>(&Vt[vi]) = vv;
    }
  }
}

// ---------------------------------------------------------------------------
// Kernel: out = Abf @ Wpt^T + b
// ---------------------------------------------------------------------------
__global__ __launch_bounds__(256) void proj_gemm(
    const unsigned short* __restrict__ Abf,  // [4096][1024] bf16
    const unsigned short* __restrict__ Wpt,  // [1024][1024] bf16 (W^T)
    const float* __restrict__ Bias,          // [1024]
    float* __restrict__ out)                 // [4096][1024] fp32
{
  __shared__ __align__(16) unsigned short lds_a[2][128][32];
  __shared__ __align__(16) unsigned short lds_b[2][128][32];

  GEMM_MAIN_LOOP(Abf, Wpt)

#pragma unroll
  for (int ni = 0; ni < 4; ++ni) {
    int c = n0 + wc * 64 + ni * 16 + lr;
    float bias = Bias[c];
#pragma unroll
    for (int mi = 0; mi < 4; ++mi) {
#pragma unroll
      for (int j = 0; j < 4; ++j) {
        int m = m0 + wr * 64 + mi * 16 + gq * 4 + j;
        out[(size_t)m * DMODEL + c] = acc[mi][ni][j] + bias;
      }
    }
  }
}

// ---------------------------------------------------------------------------
// Kernel: causal flash attention — swapped QK^T, in-register softmax,
// P routed through per-wave swizzled LDS (proven zero-conflict pattern),
// K=32 PV. Block = 64-row q-tile, 4 waves x 16 q-rows. Lane owns q = lane&15;
// S^T = mfma(K,Q) gives kv = 16ni+4gq+reg in-lane.
// ---------------------------------------------------------------------------
__global__ __launch_bounds__(256, 4) void attn_fwd(
    const unsigned short* __restrict__ Qbf,  // pre-scaled bf16 [bh][s][d]
    const unsigned short* __restrict__ Kbf,  // bf16 [bh][s][d]
    const unsigned short* __restrict__ Vtg,  // bf16 [bh][d][s]
    unsigned short* __restrict__ Abf)        // bf16 [b][s][D] merged heads
{
  __shared__ __align__(16) unsigned short K_lds[2][64][64];
  __shared__ __align__(16) unsigned short V_lds[2][64][64];
  __shared__ __align__(16) unsigned short P_lds[4][16][64];

  const int tid = threadIdx.x;
  const int lane = tid & 63;
  const int wv = tid >> 6;
  const int bid = blockIdx.x;
  const int qt = 31 - (bid >> 5);   // longest blocks dispatch first (LPT)
  const int bh = bid & 31;

  const int lr = lane & 15;
  const int gq = lane >> 4;

  const unsigned short* Kg = Kbf + (size_t)bh * (SEQ * HDIM);
  const unsigned short* Vg = Vtg + (size_t)bh * (SEQ * HDIM);
  const unsigned short* Qg = Qbf + (size_t)bh * (SEQ * HDIM)
                                 + (size_t)(qt * 64 + wv * 16) * HDIM;

  // Q B-frags: col=q=lr, k=d. qf0: d=8gq+j, qf1: d=32+8gq+j.
  s16x8 qf0 = *reinterpret_cast<const s16x8*>(&Qg[lr * 64 + (gq << 3)]);
  s16x8 qf1 = *reinterpret_cast<const s16x8*>(&Qg[lr * 64 + 32 + (gq << 3)]);

  const f32x4 fzero = {0.f, 0.f, 0.f, 0.f};
  f32x4 O[4];      // O^T tile no: d = 16no+4gq+reg, q = lr
  float mrow = -1e30f, lrow = 0.f;
#pragma unroll
  for (int no = 0; no < 4; ++no) O[no] = fzero;

#define STAGE(kv0, nb)                                                        \
  {                                                                           \
    _Pragma("unroll")                                                         \
    for (int i = 0; i < 2; ++i) {                                             \
      int L = tid + (i << 8);                                                 \
      int r = L >> 3, c = L & 7;                                              \
      int cc = (c ^ (r & 7)) << 3;                                            \
      int ubase = ((i << 8) + (wv << 6)) << 3;                                \
      gload16(&Kg[(((kv0) + r) << 6) + cc], &K_lds[nb][0][0] + ubase);        \
      gload16(&Vg[((size_t)r << 11) + (kv0) + cc], &V_lds[nb][0][0] + ubase); \
    }                                                                         \
  }

  STAGE(0, 0);

  for (int t = 0; t <= qt; ++t) {
    __syncthreads();
    if (t < qt) STAGE((t + 1) * 64, (t + 1) & 1);
    const int buf = t & 1;

    // ---- S^T = K Q^T : sc[ni][reg] = S[q=lr][kv=16ni+4gq+reg] ----
    f32x4 sc[4];
#pragma unroll
    for (int ni = 0; ni < 4; ++ni) {
      int kr = ni * 16 + lr;
      int sw = kr & 7;
      s16x8 kb0 = *reinterpret_cast<const s16x8*>(&K_lds[buf][kr][(gq ^ sw) << 3]);
      s16x8 kb1 = *reinterpret_cast<const s16x8*>(&K_lds[buf][kr][((gq + 4) ^ sw) << 3]);
      f32x4 tacc = mfma16(kb0, qf0, fzero);
      sc[ni] = mfma16(kb1, qf1, tacc);
    }

    // ---- causal mask (diag tile only): kv_local > q_local ----
    if (t == qt) {
      int qloc = wv * 16 + lr;
#pragma unroll
      for (int ni = 0; ni < 4; ++ni)
#pragma unroll
        for (int r = 0; r < 4; ++r)
          if (ni * 16 + gq * 4 + r > qloc) sc[ni][r] = -1e30f;
    }

    // ---- in-register online softmax (q = lr; 16 scores in-lane; row
    //      spread across the 4 gq-lanes -> xor16/xor32 reduce) ----
    float tmax = fmaxf(fmaxf(fmaxf(sc[0][0], sc[0][1]), fmaxf(sc[0][2], sc[0][3])),
                       fmaxf(fmaxf(sc[1][0], sc[1][1]), fmaxf(sc[1][2], sc[1][3])));
    tmax = fmaxf(tmax,
                 fmaxf(fmaxf(fmaxf(sc[2][0], sc[2][1]), fmaxf(sc[2][2], sc[2][3])),
                       fmaxf(fmaxf(sc[3][0], sc[3][1]), fmaxf(sc[3][2], sc[3][3]))));
    tmax = fmaxf(tmax, __shfl_xor(tmax, 16));
    tmax = fmaxf(tmax, __shfl_xor(tmax, 32));
    float newm = fmaxf(mrow, tmax);
    float fs = __builtin_amdgcn_exp2f(mrow - newm);
    mrow = newm;
    float rs = 0.f;
#pragma unroll
    for (int ni = 0; ni < 4; ++ni) {
#pragma unroll
      for (int r = 0; r < 4; ++r) {
        float p = __builtin_amdgcn_exp2f(sc[ni][r] - newm);
        sc[ni][r] = p;
        rs += p;
      }
    }
    rs += __shfl_xor(rs, 16);
    rs += __shfl_xor(rs, 32);
    lrow = lrow * fs + rs;
#pragma unroll
    for (int no = 0; no < 4; ++no) O[no] *= fs;

    // ---- P -> per-wave LDS (B-operand layout, swizzled chunks).
    //      Same-wave write->read: in-order LDS pipe, no barrier needed. ----
    {
      unsigned short* Prow = &P_lds[wv][lr][0];
      const int swl = lr & 7;
#pragma unroll
      for (int ni = 0; ni < 4; ++ni) {
        i32x2 d2;
        d2[0] = cvtpk(sc[ni][0], sc[ni][1]);
        d2[1] = cvtpk(sc[ni][2], sc[ni][3]);
        // kv base = 16ni+4gq: chunk = (2ni+(gq>>1))^swl, ushort off = 4*(gq&1)
        int off = ((((2 * ni) + (gq >> 1)) ^ swl) << 3) + ((gq & 1) << 2);
        *reinterpret_cast<i32x2*>(&Prow[off]) = d2;
      }
      s16x8 pB0 = *reinterpret_cast<const s16x8*>(&Prow[(gq ^ swl) << 3]);
      s16x8 pB1 = *reinterpret_cast<const s16x8*>(&Prow[((gq + 4) ^ swl) << 3]);

      // ---- O^T += V^T P^T (K=32; A = V^T rows, b128 swizzled reads) ----
#pragma unroll
      for (int no = 0; no < 4; ++no) {
        int dr = no * 16 + lr;
        int sw = dr & 7;
        s16x8 vb0 = *reinterpret_cast<const s16x8*>(&V_lds[buf][dr][(gq ^ sw) << 3]);
        s16x8 vb1 = *reinterpret_cast<const s16x8*>(&V_lds[buf][dr][((gq + 4) ^ sw) << 3]);
        O[no] = mfma16(vb0, pB0, O[no]);
        O[no] = mfma16(vb1, pB1, O[no]);
      }
    }
  }

  // ---- normalize + write merged heads (bf16); lane owns q=lr ----
  const int b = bh >> 4, h = bh & 15;
  float inv = 1.0f / lrow;
  int srow = qt * 64 + wv * 16 + lr;
  size_t base = (size_t)(b * SEQ + srow) * DMODEL + h * 64 + (gq << 2);
#pragma unroll
  for (int no = 0; no < 4; ++no) {
    s16x4 ov;
#pragma unroll
    for (int r = 0; r < 4; ++r) ov[r] = (short)f2bf(O[no][r] * inv);
    *reinterpret_cast<s16x4*>(&Abf[base + no * 16]) = ov;
  }
#undef STAGE
}

// ---------------------------------------------------------------------------
extern "C" void kernel_launch(void* const* d_in, const int* in_sizes, int n_in,
                              void* d_out, int out_size, void* d_ws, size_t ws_size,
                              hipStream_t stream) {
  const float* x        = (const float*)d_in[0];
  const float* c_attn_w = (const float*)d_in[1];
  const float* c_attn_b = (const float*)d_in[2];
  const float* c_proj_w = (const float*)d_in[3];
  const float* c_proj_b = (const float*)d_in[4];
  float* out = (float*)d_out;

  // ws layout (ushort units):
  //  [0 .. 4M)   Qbf
  //  [4M .. 8M)  Xbf (qkv) / Abf (attn+proj)  aliased by liveness
  //  [8M .. 11M) Wt (qkv) / Wpt (proj)        aliased by liveness
  unsigned short* Qbf = (unsigned short*)d_ws;
  unsigned short* Xbf = Qbf + 4194304;
  unsigned short* Abf = Xbf;
  unsigned short* Wt  = Qbf + 8388608;
  unsigned short* Wpt = Wt;
  unsigned short* Kbf = (unsigned short*)out;  // a-slot scratch
  unsigned short* Vt  = Kbf + 4194304;

  convert_x<<<dim3(4096), 256, 0, stream>>>(x, Xbf);
  convert_wt<<<dim3(48, 16), 256, 0, stream>>>(c_attn_w, Wt, NQKV);
  qkv_gemm<<<dim3(32, 24), 256, 0, stream>>>(Xbf, Wt, c_attn_b, out, Qbf);
  convert_wt<<<dim3(16, 16), 256, 0, stream>>>(c_proj_w, Wpt, DMODEL);
  attn_fwd<<<dim3(1024), 256, 0, stream>>>(Qbf, Kbf, Vt, Abf);
  proj_gemm<<<dim3(32, 8), 256, 0, stream>>>(Abf, Wpt, c_proj_b, out);
}

// Round 7
// 111.256 us; speedup vs baseline: 3.4746x; 1.0812x over previous
//
#include <hip/hip_runtime.h>
#include <hip/hip_bf16.h>
#include <cstdint>
#include <cstddef>

// Problem dims
#define SEQ 2048
#define DMODEL 1024
#define NHEAD 16
#define HDIM 64
#define MTOT 4096      // B*S
#define NQKV 3072
#define KDIM 1024

// d_out layout (floats): a[4194304] | k[4194304] | v[4194304]
#define OUT_K_BASE  4194304u
#define OUT_V_BASE  8388608u

// 0.125 * log2(e): folded into Q so QK^T scores are already in exp2 domain
#define QSCALE 0.18033688011112043f

typedef __attribute__((ext_vector_type(4))) float f32x4;
typedef __attribute__((ext_vector_type(8))) __bf16 bf16x8;
typedef __attribute__((ext_vector_type(8))) short s16x8;
typedef __attribute__((ext_vector_type(4))) short s16x4;
typedef __attribute__((ext_vector_type(2))) int i32x2;

static __device__ __forceinline__ unsigned short f2bf(float f) {
  unsigned int u = __builtin_bit_cast(unsigned int, f);
  u += 0x7FFFu + ((u >> 16) & 1u);
  return (unsigned short)(u >> 16);
}

static __device__ __forceinline__ s16x4 pack4(float4 v) {
  s16x4 r;
  r[0] = (short)f2bf(v.x);
  r[1] = (short)f2bf(v.y);
  r[2] = (short)f2bf(v.z);
  r[3] = (short)f2bf(v.w);
  return r;
}

// packed 2x f32 -> 2x bf16 in one dword (elem0 = lo)
static __device__ __forceinline__ int cvtpk(float lo, float hi) {
  int r;
  asm("v_cvt_pk_bf16_f32 %0, %1, %2" : "=v"(r) : "v"(lo), "v"(hi));
  return r;
}

static __device__ __forceinline__ f32x4 mfma16(s16x8 a, s16x8 b, f32x4 c) {
  return __builtin_amdgcn_mfma_f32_16x16x32_bf16(
      __builtin_bit_cast(bf16x8, a), __builtin_bit_cast(bf16x8, b), c, 0, 0, 0);
}

// async global->LDS, 16B per lane. LDS dest: wave-uniform base + lane*16.
static __device__ __forceinline__ void gload16(const void* g, void* l) {
  __builtin_amdgcn_global_load_lds(
      (const __attribute__((address_space(1))) unsigned int*)(uintptr_t)g,
      (__attribute__((address_space(3))) unsigned int*)(uintptr_t)l,
      16, 0, 0);
}

// ---------------------------------------------------------------------------
// Pre-pass: X (fp32 [4096][1024]) -> Xbf (bf16, same layout)
// ---------------------------------------------------------------------------
__global__ __launch_bounds__(256) void convert_x(
    const float* __restrict__ X, unsigned short* __restrict__ Xbf)
{
  int i = blockIdx.x * 256 + threadIdx.x;   // float4 index, 1M total
  float4 v = reinterpret_cast<const float4*>(X)[i];
  reinterpret_cast<s16x4*>(Xbf)[i] = pack4(v);
}

// ---------------------------------------------------------------------------
// Pre-pass: W (fp32 [1024][N]) -> Wt (bf16 [N][1024]) tiled transpose via LDS
// grid = (N/64, 16)
// ---------------------------------------------------------------------------
__global__ __launch_bounds__(256) void convert_wt(
    const float* __restrict__ W, unsigned short* __restrict__ Wt, int N)
{
  __shared__ unsigned short t[64][72];
  const int n0 = blockIdx.x * 64, k0 = blockIdx.y * 64;
  const int tid = threadIdx.x;
#pragma unroll
  for (int i = 0; i < 4; ++i) {
    int f = tid + (i << 8);
    int r = f >> 4, c4 = (f & 15) << 2;
    float4 v = *reinterpret_cast<const float4*>(&W[(size_t)(k0 + r) * N + n0 + c4]);
    *reinterpret_cast<s16x4*>(&t[r][c4]) = pack4(v);
  }
  __syncthreads();
#pragma unroll
  for (int i = 0; i < 2; ++i) {
    int g = tid + (i << 8);
    int n = g >> 3, k8 = (g & 7) << 3;
    s16x8 o;
#pragma unroll
    for (int jj = 0; jj < 8; ++jj) o[jj] = (short)t[k8 + jj][n];
    *reinterpret_cast<s16x8*>(&Wt[(size_t)(n0 + n) * KDIM + k0 + k8]) = o;
  }
}

// ---------------------------------------------------------------------------
// Kernel: qkv = Xbf @ Wt^T + b; route q/k/v.
// 256x256 tile, 8 waves (2M x 4N, each 128x64 output), BK=32,
// double-buffered 64KB LDS, stage-early 2-phase, chunk XOR-swizzle
// ((r>>1)&3) via pre-swizzled global source (gload_lds dest linear).
// Grid (16,12) = 192 blocks = one full-chip round.
// ---------------------------------------------------------------------------
__global__ __launch_bounds__(512, 2) void qkv_gemm(
    const unsigned short* __restrict__ Xbf,  // [4096][1024] bf16
    const unsigned short* __restrict__ Wt,   // [3072][1024] bf16 (W^T)
    const float* __restrict__ Bias,          // [3072]
    float* out,                              // d_out
    unsigned short* __restrict__ Qbf)
{
  __shared__ __align__(16) unsigned short lds_a[2][256][32];  // 32 KB
  __shared__ __align__(16) unsigned short lds_b[2][256][32];  // 32 KB

  unsigned short* Kbf = (unsigned short*)out;   // a-slot scratch, 8 MiB
  unsigned short* Vt  = Kbf + 4194304;          // a-slot scratch, 8 MiB

  const int tid = threadIdx.x;
  const int lane = tid & 63;
  const int wv = tid >> 6;        // 0..7
  const int wr = wv >> 2;         // 0..1  (M half)
  const int wc = wv & 3;          // 0..3  (N quarter)
  const int m0 = blockIdx.x * 256;
  const int n0 = blockIdx.y * 256;
  const int lr = lane & 15;
  const int gq = lane >> 4;

  const f32x4 fzero = {0.f, 0.f, 0.f, 0.f};
  f32x4 acc[8][4];
#pragma unroll
  for (int i = 0; i < 8; ++i)
#pragma unroll
    for (int j = 0; j < 4; ++j) acc[i][j] = fzero;

  {
    // staging: per array 1024 chunks (256 rows x 4), 2 per thread
    const int r0 = tid >> 2;            // 0..127
    const int r1 = r0 + 128;
    const int c0 = tid & 3;
    const int sc0 = ((c0 ^ ((r0 >> 1) & 3)) << 3);
    const int sc1 = ((c0 ^ ((r1 >> 1) & 3)) << 3);
    const int ub0 = (wv << 6) << 3;
    const int ub1 = ((1 << 9) + (wv << 6)) << 3;
    auto stage = [&](int nb, int kk) {
      gload16(&Xbf[(size_t)(m0 + r0) * KDIM + kk + sc0], &lds_a[nb][0][0] + ub0);
      gload16(&Xbf[(size_t)(m0 + r1) * KDIM + kk + sc1], &lds_a[nb][0][0] + ub1);
      gload16(&Wt[(size_t)(n0 + r0) * KDIM + kk + sc0], &lds_b[nb][0][0] + ub0);
      gload16(&Wt[(size_t)(n0 + r1) * KDIM + kk + sc1], &lds_b[nb][0][0] + ub1);
    };
    stage(0, 0);
    for (int t = 0; t < 32; ++t) {
      __syncthreads();                  // buf[t&1] staged (vmcnt drained)
      if (t < 31) stage((t + 1) & 1, (t + 1) << 5);
      const int bufg = t & 1;
      s16x8 bfv[4];
#pragma unroll
      for (int ni = 0; ni < 4; ++ni) {
        int row = wc * 64 + ni * 16 + lr;
        bfv[ni] = *reinterpret_cast<const s16x8*>(
            &lds_b[bufg][row][(gq ^ ((row >> 1) & 3)) << 3]);
      }
#pragma unroll
      for (int mi = 0; mi < 8; ++mi) {
        int row = wr * 128 + mi * 16 + lr;
        s16x8 af = *reinterpret_cast<const s16x8*>(
            &lds_a[bufg][row][(gq ^ ((row >> 1) & 3)) << 3]);
#pragma unroll
        for (int ni = 0; ni < 4; ++ni)
          acc[mi][ni] = mfma16(af, bfv[ni], acc[mi][ni]);
      }
    }
  }

  const int seg = n0 >> 10;   // 0=q 1=k 2=v (block-uniform; 4 y-blocks/seg)

  if (seg == 0) {
#pragma unroll
    for (int ni = 0; ni < 4; ++ni) {
      int c = n0 + wc * 64 + ni * 16 + lr;
      float bias = Bias[c];
      int h = (c & 1023) >> 6, d = c & 63;
#pragma unroll
      for (int mi = 0; mi < 8; ++mi)
#pragma unroll
        for (int j = 0; j < 4; ++j) {
          int m = m0 + wr * 128 + mi * 16 + gq * 4 + j;
          int b = m >> 11, s = m & 2047;
          Qbf[(size_t)((b * NHEAD + h) * SEQ + s) * HDIM + d] =
              f2bf((acc[mi][ni][j] + bias) * QSCALE);
        }
    }
  } else if (seg == 1) {
#pragma unroll
    for (int ni = 0; ni < 4; ++ni) {
      int c = n0 + wc * 64 + ni * 16 + lr;
      float bias = Bias[c];
      int h = (c & 1023) >> 6, d = c & 63;
#pragma unroll
      for (int mi = 0; mi < 8; ++mi)
#pragma unroll
        for (int j = 0; j < 4; ++j) {
          int m = m0 + wr * 128 + mi * 16 + gq * 4 + j;
          int b = m >> 11, s = m & 2047;
          float val = acc[mi][ni][j] + bias;
          size_t idx = (size_t)((b * NHEAD + h) * SEQ + s) * HDIM + d;
          out[OUT_K_BASE + idx] = val;
          Kbf[idx] = f2bf(val);
        }
    }
  } else {
    // V block: fp32 present store + per-wave 64x64 LDS transpose (2 halves)
    // for coalesced Vt stores. Per-wave T region: 4096 ushorts (8KB).
    __syncthreads();   // all waves done with main-loop LDS
    unsigned short* T = (wv < 4) ? (&lds_a[0][0][0] + (wv << 12))
                                 : (&lds_b[0][0][0] + ((wv - 4) << 12));
    const int b = m0 >> 11;
    const int s0 = (m0 & 2047) + wr * 128;
    const int h = (n0 >> 6) - 32 + wc;
#pragma unroll
    for (int h2 = 0; h2 < 2; ++h2) {
#pragma unroll
      for (int ni = 0; ni < 4; ++ni) {
        int c = n0 + wc * 64 + ni * 16 + lr;
        float bias = Bias[c];
        int d_loc = ni * 16 + lr;
        int dsw = d_loc & 7;
#pragma unroll
        for (int mh = 0; mh < 4; ++mh) {
          int mi = h2 * 4 + mh;
#pragma unroll
          for (int j = 0; j < 4; ++j) {
            int s_loc = mi * 16 + gq * 4 + j;      // 0..127
            int ss = s_loc - (h2 << 6);            // 0..63 within half
            float val = acc[mi][ni][j] + bias;
            out[OUT_V_BASE +
                (size_t)((b * NHEAD + h) * SEQ + s0 + s_loc) * HDIM + d_loc] = val;
            T[d_loc * 64 + (((ss >> 3) ^ dsw) << 3) + (ss & 7)] = f2bf(val);
          }
        }
      }
      // read back transposed, coalesced 16B stores (same-wave, in-order LDS)
#pragma unroll
      for (int it = 0; it < 8; ++it) {
        int dl = (lane >> 3) + (it << 3);
        int cl = lane & 7;
        s16x8 vv = *reinterpret_cast<const s16x8*>(
            &T[dl * 64 + ((cl ^ (dl & 7)) << 3)]);
        size_t vi = (((size_t)(b * NHEAD + h) * HDIM + dl) << 11) +
                    s0 + (h2 << 6) + (cl << 3);
        *reinterpret_cast<s16x8*>(&Vt[vi]) = vv;
      }
    }
  }
}

// ---------------------------------------------------------------------------
// Kernel: out = Abf @ Wpt^T + b. 128x128 tile, 4 waves, BK=64,
// double-buffered 64KB LDS, full (r&7) chunk swizzle (proven zero-conflict).
// Grid (32,8) = 256 blocks = one full-chip round.
// ---------------------------------------------------------------------------
__global__ __launch_bounds__(256) void proj_gemm(
    const unsigned short* __restrict__ Abf,  // [4096][1024] bf16
    const unsigned short* __restrict__ Wpt,  // [1024][1024] bf16 (W^T)
    const float* __restrict__ Bias,          // [1024]
    float* __restrict__ out)                 // [4096][1024] fp32
{
  __shared__ __align__(16) unsigned short lds_a[2][128][64];  // 32 KB
  __shared__ __align__(16) unsigned short lds_b[2][128][64];  // 32 KB

  const int tid = threadIdx.x;
  const int lane = tid & 63;
  const int wv = tid >> 6;
  const int wr = wv >> 1, wc = wv & 1;
  const int m0 = blockIdx.x * 128;
  const int n0 = blockIdx.y * 128;
  const int lr = lane & 15;
  const int gq = lane >> 4;

  const f32x4 fzero = {0.f, 0.f, 0.f, 0.f};
  f32x4 acc[4][4];
#pragma unroll
  for (int i = 0; i < 4; ++i)
#pragma unroll
    for (int j = 0; j < 4; ++j) acc[i][j] = fzero;

  {
    // per array 1024 chunks (128 rows x 8), 4 per thread
    const int r0 = tid >> 3;            // 0..31
    const int c0 = tid & 7;
    auto stage = [&](int nb, int kk) {
#pragma unroll
      for (int i = 0; i < 4; ++i) {
        int r = r0 + (i << 5);
        int sc = ((c0 ^ (r & 7)) << 3);
        int ub = (((i << 8) + (wv << 6)) << 3);
        gload16(&Abf[(size_t)(m0 + r) * KDIM + kk + sc], &lds_a[nb][0][0] + ub);
        gload16(&Wpt[(size_t)(n0 + r) * KDIM + kk + sc], &lds_b[nb][0][0] + ub);
      }
    };
    stage(0, 0);
    for (int t = 0; t < 16; ++t) {
      __syncthreads();
      if (t < 15) stage((t + 1) & 1, (t + 1) << 6);
      const int bufg = t & 1;
#pragma unroll
      for (int kf = 0; kf < 2; ++kf) {
        s16x8 bfv[4];
#pragma unroll
        for (int ni = 0; ni < 4; ++ni) {
          int row = wc * 64 + ni * 16 + lr;
          bfv[ni] = *reinterpret_cast<const s16x8*>(
              &lds_b[bufg][row][((kf * 4 + gq) ^ (row & 7)) << 3]);
        }
#pragma unroll
        for (int mi = 0; mi < 4; ++mi) {
          int row = wr * 64 + mi * 16 + lr;
          s16x8 af = *reinterpret_cast<const s16x8*>(
              &lds_a[bufg][row][((kf * 4 + gq) ^ (row & 7)) << 3]);
#pragma unroll
          for (int ni = 0; ni < 4; ++ni)
            acc[mi][ni] = mfma16(af, bfv[ni], acc[mi][ni]);
        }
      }
    }
  }

#pragma unroll
  for (int ni = 0; ni < 4; ++ni) {
    int c = n0 + wc * 64 + ni * 16 + lr;
    float bias = Bias[c];
#pragma unroll
    for (int mi = 0; mi < 4; ++mi) {
#pragma unroll
      for (int j = 0; j < 4; ++j) {
        int m = m0 + wr * 64 + mi * 16 + gq * 4 + j;
        out[(size_t)m * DMODEL + c] = acc[mi][ni][j] + bias;
      }
    }
  }
}

// ---------------------------------------------------------------------------
// Kernel: causal flash attention — swapped QK^T, in-register softmax,
// P routed through per-wave swizzled LDS, K=32 PV. (Unchanged from R6.)
// ---------------------------------------------------------------------------
__global__ __launch_bounds__(256, 4) void attn_fwd(
    const unsigned short* __restrict__ Qbf,  // pre-scaled bf16 [bh][s][d]
    const unsigned short* __restrict__ Kbf,  // bf16 [bh][s][d]
    const unsigned short* __restrict__ Vtg,  // bf16 [bh][d][s]
    unsigned short* __restrict__ Abf)        // bf16 [b][s][D] merged heads
{
  __shared__ __align__(16) unsigned short K_lds[2][64][64];
  __shared__ __align__(16) unsigned short V_lds[2][64][64];
  __shared__ __align__(16) unsigned short P_lds[4][16][64];

  const int tid = threadIdx.x;
  const int lane = tid & 63;
  const int wv = tid >> 6;
  const int bid = blockIdx.x;
  const int qt = 31 - (bid >> 5);   // longest blocks dispatch first (LPT)
  const int bh = bid & 31;

  const int lr = lane & 15;
  const int gq = lane >> 4;

  const unsigned short* Kg = Kbf + (size_t)bh * (SEQ * HDIM);
  const unsigned short* Vg = Vtg + (size_t)bh * (SEQ * HDIM);
  const unsigned short* Qg = Qbf + (size_t)bh * (SEQ * HDIM)
                                 + (size_t)(qt * 64 + wv * 16) * HDIM;

  s16x8 qf0 = *reinterpret_cast<const s16x8*>(&Qg[lr * 64 + (gq << 3)]);
  s16x8 qf1 = *reinterpret_cast<const s16x8*>(&Qg[lr * 64 + 32 + (gq << 3)]);

  const f32x4 fzero = {0.f, 0.f, 0.f, 0.f};
  f32x4 O[4];      // O^T tile no: d = 16no+4gq+reg, q = lr
  float mrow = -1e30f, lrow = 0.f;
#pragma unroll
  for (int no = 0; no < 4; ++no) O[no] = fzero;

#define STAGE(kv0, nb)                                                        \
  {                                                                           \
    _Pragma("unroll")                                                         \
    for (int i = 0; i < 2; ++i) {                                             \
      int L = tid + (i << 8);                                                 \
      int r = L >> 3, c = L & 7;                                              \
      int cc = (c ^ (r & 7)) << 3;                                            \
      int ubase = ((i << 8) + (wv << 6)) << 3;                                \
      gload16(&Kg[(((kv0) + r) << 6) + cc], &K_lds[nb][0][0] + ubase);        \
      gload16(&Vg[((size_t)r << 11) + (kv0) + cc], &V_lds[nb][0][0] + ubase); \
    }                                                                         \
  }

  STAGE(0, 0);

  for (int t = 0; t <= qt; ++t) {
    __syncthreads();
    if (t < qt) STAGE((t + 1) * 64, (t + 1) & 1);
    const int buf = t & 1;

    // ---- S^T = K Q^T : sc[ni][reg] = S[q=lr][kv=16ni+4gq+reg] ----
    f32x4 sc[4];
#pragma unroll
    for (int ni = 0; ni < 4; ++ni) {
      int kr = ni * 16 + lr;
      int sw = kr & 7;
      s16x8 kb0 = *reinterpret_cast<const s16x8*>(&K_lds[buf][kr][(gq ^ sw) << 3]);
      s16x8 kb1 = *reinterpret_cast<const s16x8*>(&K_lds[buf][kr][((gq + 4) ^ sw) << 3]);
      f32x4 tacc = mfma16(kb0, qf0, fzero);
      sc[ni] = mfma16(kb1, qf1, tacc);
    }

    if (t == qt) {
      int qloc = wv * 16 + lr;
#pragma unroll
      for (int ni = 0; ni < 4; ++ni)
#pragma unroll
        for (int r = 0; r < 4; ++r)
          if (ni * 16 + gq * 4 + r > qloc) sc[ni][r] = -1e30f;
    }

    // ---- in-register online softmax ----
    float tmax = fmaxf(fmaxf(fmaxf(sc[0][0], sc[0][1]), fmaxf(sc[0][2], sc[0][3])),
                       fmaxf(fmaxf(sc[1][0], sc[1][1]), fmaxf(sc[1][2], sc[1][3])));
    tmax = fmaxf(tmax,
                 fmaxf(fmaxf(fmaxf(sc[2][0], sc[2][1]), fmaxf(sc[2][2], sc[2][3])),
                       fmaxf(fmaxf(sc[3][0], sc[3][1]), fmaxf(sc[3][2], sc[3][3]))));
    tmax = fmaxf(tmax, __shfl_xor(tmax, 16));
    tmax = fmaxf(tmax, __shfl_xor(tmax, 32));
    float newm = fmaxf(mrow, tmax);
    float fs = __builtin_amdgcn_exp2f(mrow - newm);
    mrow = newm;
    float rs = 0.f;
#pragma unroll
    for (int ni = 0; ni < 4; ++ni) {
#pragma unroll
      for (int r = 0; r < 4; ++r) {
        float p = __builtin_amdgcn_exp2f(sc[ni][r] - newm);
        sc[ni][r] = p;
        rs += p;
      }
    }
    rs += __shfl_xor(rs, 16);
    rs += __shfl_xor(rs, 32);
    lrow = lrow * fs + rs;
#pragma unroll
    for (int no = 0; no < 4; ++no) O[no] *= fs;

    // ---- P -> per-wave LDS (B-operand layout, swizzled chunks) ----
    {
      unsigned short* Prow = &P_lds[wv][lr][0];
      const int swl = lr & 7;
#pragma unroll
      for (int ni = 0; ni < 4; ++ni) {
        i32x2 d2;
        d2[0] = cvtpk(sc[ni][0], sc[ni][1]);
        d2[1] = cvtpk(sc[ni][2], sc[ni][3]);
        int off = ((((2 * ni) + (gq >> 1)) ^ swl) << 3) + ((gq & 1) << 2);
        *reinterpret_cast<i32x2*>(&Prow[off]) = d2;
      }
      s16x8 pB0 = *reinterpret_cast<const s16x8*>(&Prow[(gq ^ swl) << 3]);
      s16x8 pB1 = *reinterpret_cast<const s16x8*>(&Prow[((gq + 4) ^ swl) << 3]);

#pragma unroll
      for (int no = 0; no < 4; ++no) {
        int dr = no * 16 + lr;
        int sw = dr & 7;
        s16x8 vb0 = *reinterpret_cast<const s16x8*>(&V_lds[buf][dr][(gq ^ sw) << 3]);
        s16x8 vb1 = *reinterpret_cast<const s16x8*>(&V_lds[buf][dr][((gq + 4) ^ sw) << 3]);
        O[no] = mfma16(vb0, pB0, O[no]);
        O[no] = mfma16(vb1, pB1, O[no]);
      }
    }
  }

  const int b = bh >> 4, h = bh & 15;
  float inv = 1.0f / lrow;
  int srow = qt * 64 + wv * 16 + lr;
  size_t base = (size_t)(b * SEQ + srow) * DMODEL + h * 64 + (gq << 2);
#pragma unroll
  for (int no = 0; no < 4; ++no) {
    s16x4 ov;
#pragma unroll
    for (int r = 0; r < 4; ++r) ov[r] = (short)f2bf(O[no][r] * inv);
    *reinterpret_cast<s16x4*>(&Abf[base + no * 16]) = ov;
  }
#undef STAGE
}

// ---------------------------------------------------------------------------
extern "C" void kernel_launch(void* const* d_in, const int* in_sizes, int n_in,
                              void* d_out, int out_size, void* d_ws, size_t ws_size,
                              hipStream_t stream) {
  const float* x        = (const float*)d_in[0];
  const float* c_attn_w = (const float*)d_in[1];
  const float* c_attn_b = (const float*)d_in[2];
  const float* c_proj_w = (const float*)d_in[3];
  const float* c_proj_b = (const float*)d_in[4];
  float* out = (float*)d_out;

  // ws layout (ushort units):
  //  [0 .. 4M)   Qbf
  //  [4M .. 8M)  Xbf (qkv) / Abf (attn+proj)  aliased by liveness
  //  [8M .. 11M) Wt (qkv) / Wpt (proj)        aliased by liveness
  unsigned short* Qbf = (unsigned short*)d_ws;
  unsigned short* Xbf = Qbf + 4194304;
  unsigned short* Abf = Xbf;
  unsigned short* Wt  = Qbf + 8388608;
  unsigned short* Wpt = Wt;
  unsigned short* Kbf = (unsigned short*)out;  // a-slot scratch
  unsigned short* Vt  = Kbf + 4194304;

  convert_x<<<dim3(4096), 256, 0, stream>>>(x, Xbf);
  convert_wt<<<dim3(48, 16), 256, 0, stream>>>(c_attn_w, Wt, NQKV);
  qkv_gemm<<<dim3(16, 12), 512, 0, stream>>>(Xbf, Wt, c_attn_b, out, Qbf);
  convert_wt<<<dim3(16, 16), 256, 0, stream>>>(c_proj_w, Wpt, DMODEL);
  attn_fwd<<<dim3(1024), 256, 0, stream>>>(Qbf, Kbf, Vt, Abf);
  proj_gemm<<<dim3(32, 8), 256, 0, stream>>>(Abf, Wpt, c_proj_b, out);
}